// Round 1
// baseline (2245.590 us; speedup 1.0000x reference)
//
#include <hip/hip_runtime.h>
#include <hip/hip_bf16.h>

#define N_NODES 100000
#define N_EDGES 1600000

// ---------------- CSR build ----------------

__global__ __launch_bounds__(256) void count_deg(const int* __restrict__ dst,
                                                 int* __restrict__ counts, int ne) {
    int e = blockIdx.x * blockDim.x + threadIdx.x;
    if (e < ne) atomicAdd(&counts[dst[e]], 1);
}

// single-block exclusive scan over counts -> offsets[0..n]; also inv_deg
__global__ __launch_bounds__(1024) void scan_offsets(const int* __restrict__ counts,
                                                     int* __restrict__ offsets,
                                                     float* __restrict__ inv_deg, int n) {
    __shared__ int sums[1024];
    int tid = threadIdx.x;
    int chunk = (n + 1023) >> 10;
    int b = tid * chunk;
    int e = min(b + chunk, n);
    int s = 0;
    for (int i = b; i < e; ++i) s += counts[i];
    sums[tid] = s;
    __syncthreads();
    for (int off = 1; off < 1024; off <<= 1) {
        int v = (tid >= off) ? sums[tid - off] : 0;
        __syncthreads();
        sums[tid] += v;
        __syncthreads();
    }
    int run = (tid == 0) ? 0 : sums[tid - 1];
    for (int i = b; i < e; ++i) {
        offsets[i] = run;
        int c = counts[i];
        inv_deg[i] = 1.0f / (float)max(c, 1);
        run += c;
    }
    if (tid == 1023) offsets[n] = sums[1023];
}

__global__ __launch_bounds__(256) void fill_csr(const int* __restrict__ src,
                                                const int* __restrict__ dst,
                                                int* __restrict__ cursor,
                                                int* __restrict__ sorted_src, int ne) {
    int e = blockIdx.x * blockDim.x + threadIdx.x;
    if (e < ne) {
        int p = atomicAdd(&cursor[dst[e]], 1);
        sorted_src[p] = src[e];
    }
}

// ---------------- per-layer kernels ----------------

// one thread per (node, feature); consecutive threads cover consecutive features
// -> coalesced gather of h[src] rows. No atomics.
template <int Cin>
__global__ __launch_bounds__(256) void aggregate(const float* __restrict__ h,
                                                 const int* __restrict__ offs,
                                                 const int* __restrict__ ssrc,
                                                 const float* __restrict__ inv_deg,
                                                 float* __restrict__ agg, int nnodes) {
    int t = blockIdx.x * blockDim.x + threadIdx.x;
    if (t >= nnodes * Cin) return;
    int node = t / Cin;          // Cin is power of 2 -> shift
    int c = t - node * Cin;
    int b = offs[node], e = offs[node + 1];
    float acc = 0.f;
    for (int i = b; i < e; ++i) {
        acc += h[ssrc[i] * Cin + c];
    }
    agg[t] = acc * inv_deg[node];
}

// out = relu(agg @ Wl + bl + h @ Wr); one thread per output element
template <int Cin, int Cout, bool RELU>
__global__ __launch_bounds__(256) void sage_linear(const float* __restrict__ agg,
                                                   const float* __restrict__ h,
                                                   const float* __restrict__ Wl,
                                                   const float* __restrict__ bl,
                                                   const float* __restrict__ Wr,
                                                   float* __restrict__ out, int nnodes) {
    int t = blockIdx.x * blockDim.x + threadIdx.x;
    if (t >= nnodes * Cout) return;
    int node = t / Cout;
    int c = t - node * Cout;
    const float* __restrict__ ar = agg + node * Cin;
    const float* __restrict__ hr = h + node * Cin;
    float acc = bl[c];
#pragma unroll
    for (int k = 0; k < Cin; ++k) {
        acc = fmaf(ar[k], Wl[k * Cout + c], acc);
        acc = fmaf(hr[k], Wr[k * Cout + c], acc);
    }
    if (RELU) acc = fmaxf(acc, 0.f);
    out[t] = acc;
}

// final projection: h(100000x32) @ W(32x1) + b
__global__ __launch_bounds__(256) void out_proj(const float* __restrict__ h,
                                                const float* __restrict__ W,
                                                const float* __restrict__ b,
                                                float* __restrict__ out, int nnodes) {
    int n = blockIdx.x * blockDim.x + threadIdx.x;
    if (n >= nnodes) return;
    float acc = b[0];
#pragma unroll
    for (int k = 0; k < 32; ++k) acc = fmaf(h[n * 32 + k], W[k], acc);
    out[n] = acc;
}

// ---------------- launch ----------------

extern "C" void kernel_launch(void* const* d_in, const int* in_sizes, int n_in,
                              void* d_out, int out_size, void* d_ws, size_t ws_size,
                              hipStream_t stream) {
    const float* x      = (const float*)d_in[0];
    const int*   ei     = (const int*)d_in[1];   // [2, E]: src = ei[0..E), dst = ei[E..2E)
    const float* Wl1    = (const float*)d_in[3];
    const float* bl1    = (const float*)d_in[4];
    const float* Wr1    = (const float*)d_in[5];
    const float* Wl2    = (const float*)d_in[6];
    const float* bl2    = (const float*)d_in[7];
    const float* Wr2    = (const float*)d_in[8];
    const float* Wl3    = (const float*)d_in[9];
    const float* bl3    = (const float*)d_in[10];
    const float* Wr3    = (const float*)d_in[11];
    const float* Wl4    = (const float*)d_in[12];
    const float* bl4    = (const float*)d_in[13];
    const float* Wr4    = (const float*)d_in[14];
    const float* Wl5    = (const float*)d_in[15];
    const float* bl5    = (const float*)d_in[16];
    const float* Wr5    = (const float*)d_in[17];
    const float* W_out  = (const float*)d_in[18];
    const float* b_out  = (const float*)d_in[19];
    float* out = (float*)d_out;

    const int N = N_NODES, E = N_EDGES;
    const int* e_src = ei;
    const int* e_dst = ei + E;

    // workspace carve-up
    size_t off = 0;
    auto carve = [&](size_t bytes) {
        void* p = (char*)d_ws + off;
        off += (bytes + 255) & ~(size_t)255;
        return p;
    };
    int*   counts  = (int*)carve((size_t)N * 4);
    int*   offsets = (int*)carve((size_t)(N + 1) * 4);
    int*   cursor  = (int*)carve((size_t)N * 4);
    float* inv_deg = (float*)carve((size_t)N * 4);
    int*   ssrc    = (int*)carve((size_t)E * 4);
    float* agg     = (float*)carve((size_t)N * 128 * 4);
    float* bufA    = (float*)carve((size_t)N * 128 * 4);
    float* bufB    = (float*)carve((size_t)N * 128 * 4);

    // --- CSR build ---
    hipMemsetAsync(counts, 0, (size_t)N * 4, stream);
    {
        int blocks = (E + 255) / 256;
        count_deg<<<blocks, 256, 0, stream>>>(e_dst, counts, E);
    }
    scan_offsets<<<1, 1024, 0, stream>>>(counts, offsets, inv_deg, N);
    hipMemcpyAsync(cursor, offsets, (size_t)N * 4, hipMemcpyDeviceToDevice, stream);
    {
        int blocks = (E + 255) / 256;
        fill_csr<<<blocks, 256, 0, stream>>>(e_src, e_dst, cursor, ssrc, E);
    }

    // --- layer 1: 2 -> 128 ---
    aggregate<2><<<(N * 2 + 255) / 256, 256, 0, stream>>>(x, offsets, ssrc, inv_deg, agg, N);
    sage_linear<2, 128, true><<<(N * 128 + 255) / 256, 256, 0, stream>>>(
        agg, x, Wl1, bl1, Wr1, bufA, N);

    // --- layer 2: 128 -> 128 ---
    aggregate<128><<<(N * 128 + 255) / 256, 256, 0, stream>>>(bufA, offsets, ssrc, inv_deg, agg, N);
    sage_linear<128, 128, true><<<(N * 128 + 255) / 256, 256, 0, stream>>>(
        agg, bufA, Wl2, bl2, Wr2, bufB, N);

    // --- layer 3: 128 -> 32 ---
    aggregate<128><<<(N * 128 + 255) / 256, 256, 0, stream>>>(bufB, offsets, ssrc, inv_deg, agg, N);
    sage_linear<128, 32, true><<<(N * 32 + 255) / 256, 256, 0, stream>>>(
        agg, bufB, Wl3, bl3, Wr3, bufA, N);

    // --- layer 4: 32 -> 32 ---
    aggregate<32><<<(N * 32 + 255) / 256, 256, 0, stream>>>(bufA, offsets, ssrc, inv_deg, agg, N);
    sage_linear<32, 32, true><<<(N * 32 + 255) / 256, 256, 0, stream>>>(
        agg, bufA, Wl4, bl4, Wr4, bufB, N);

    // --- layer 5: 32 -> 32 ---
    aggregate<32><<<(N * 32 + 255) / 256, 256, 0, stream>>>(bufB, offsets, ssrc, inv_deg, agg, N);
    sage_linear<32, 32, true><<<(N * 32 + 255) / 256, 256, 0, stream>>>(
        agg, bufB, Wl5, bl5, Wr5, bufA, N);

    // --- output projection ---
    out_proj<<<(N + 255) / 256, 256, 0, stream>>>(bufA, W_out, b_out, out, N);
}

// Round 2
// 1612.343 us; speedup vs baseline: 1.3927x; 1.3927x over previous
//
#include <hip/hip_runtime.h>
#include <hip/hip_bf16.h>

#define N_NODES 100000
#define N_EDGES 1600000

// ---------------- CSR build ----------------

__global__ __launch_bounds__(256) void count_deg(const int* __restrict__ dst,
                                                 int* __restrict__ counts, int ne) {
    int e = blockIdx.x * blockDim.x + threadIdx.x;
    if (e < ne) atomicAdd(&counts[dst[e]], 1);
}

// single-block exclusive scan over counts -> offsets[0..n]; also inv_deg
__global__ __launch_bounds__(1024) void scan_offsets(const int* __restrict__ counts,
                                                     int* __restrict__ offsets,
                                                     float* __restrict__ inv_deg, int n) {
    __shared__ int sums[1024];
    int tid = threadIdx.x;
    int chunk = (n + 1023) >> 10;
    int b = tid * chunk;
    int e = min(b + chunk, n);
    int s = 0;
    for (int i = b; i < e; ++i) s += counts[i];
    sums[tid] = s;
    __syncthreads();
    for (int off = 1; off < 1024; off <<= 1) {
        int v = (tid >= off) ? sums[tid - off] : 0;
        __syncthreads();
        sums[tid] += v;
        __syncthreads();
    }
    int run = (tid == 0) ? 0 : sums[tid - 1];
    for (int i = b; i < e; ++i) {
        offsets[i] = run;
        int c = counts[i];
        inv_deg[i] = 1.0f / (float)max(c, 1);
        run += c;
    }
    if (tid == 1023) offsets[n] = sums[1023];
}

__global__ __launch_bounds__(256) void fill_csr(const int* __restrict__ src,
                                                const int* __restrict__ dst,
                                                int* __restrict__ cursor,
                                                int* __restrict__ sorted_src, int ne) {
    int e = blockIdx.x * blockDim.x + threadIdx.x;
    if (e < ne) {
        int p = atomicAdd(&cursor[dst[e]], 1);
        sorted_src[p] = src[e];
    }
}

// ---------------- aggregation ----------------

// float4 gather: one thread per (node, 4-feature group). Consecutive threads
// cover consecutive float4s of the same source row -> coalesced.
template <int Cin>
__global__ __launch_bounds__(256) void aggregate4(const float* __restrict__ h,
                                                  const int* __restrict__ offs,
                                                  const int* __restrict__ ssrc,
                                                  const float* __restrict__ inv_deg,
                                                  float* __restrict__ agg, int nnodes) {
    constexpr int C4 = Cin / 4;
    int t = blockIdx.x * blockDim.x + threadIdx.x;
    if (t >= nnodes * C4) return;
    int node = t / C4;
    int c = t - node * C4;
    int b = offs[node], e = offs[node + 1];
    const float4* __restrict__ h4 = (const float4*)h;
    float4 acc = make_float4(0.f, 0.f, 0.f, 0.f);
    for (int i = b; i < e; ++i) {
        float4 v = h4[(size_t)ssrc[i] * C4 + c];
        acc.x += v.x; acc.y += v.y; acc.z += v.z; acc.w += v.w;
    }
    float s = inv_deg[node];
    acc.x *= s; acc.y *= s; acc.z *= s; acc.w *= s;
    ((float4*)agg)[t] = acc;
}

// Cin=2 special case: one thread per node, float2
__global__ __launch_bounds__(256) void aggregate2(const float* __restrict__ h,
                                                  const int* __restrict__ offs,
                                                  const int* __restrict__ ssrc,
                                                  const float* __restrict__ inv_deg,
                                                  float* __restrict__ agg, int nnodes) {
    int node = blockIdx.x * blockDim.x + threadIdx.x;
    if (node >= nnodes) return;
    int b = offs[node], e = offs[node + 1];
    const float2* __restrict__ h2 = (const float2*)h;
    float2 acc = make_float2(0.f, 0.f);
    for (int i = b; i < e; ++i) {
        float2 v = h2[ssrc[i]];
        acc.x += v.x; acc.y += v.y;
    }
    float s = inv_deg[node];
    acc.x *= s; acc.y *= s;
    ((float2*)agg)[node] = acc;
}

// ---------------- tiled GEMM: C = relu(agg@Wl + bl + h@Wr) ----------------
// Block computes BM x BN tile of C; BK=32 K-chunks over both (agg,Wl) and (h,Wr).
// 256 threads, each a TM x TN micro-tile.

template <int Cin, int Cout, int BM, int BN, bool RELU>
__global__ __launch_bounds__(256) void sage_gemm(const float* __restrict__ A0, // agg [M x Cin]
                                                 const float* __restrict__ A1, // h   [M x Cin]
                                                 const float* __restrict__ W0, // Wl  [Cin x Cout]
                                                 const float* __restrict__ bias,
                                                 const float* __restrict__ W1, // Wr  [Cin x Cout]
                                                 float* __restrict__ C, int M) {
    constexpr int BK = 32;
    constexpr int TM = 4;
    constexpr int TN = (BM * BN) / (256 * TM);
    static_assert(TN >= 1 && (BM * BN) == 256 * TM * TN, "tile config");
    constexpr int APAD = 4, WPAD = 4;   // +4 floats keeps float4 alignment, breaks bank stride

    __shared__ float sA0[BK][BM + APAD];
    __shared__ float sA1[BK][BM + APAD];
    __shared__ float sW0[BK][BN + WPAD];
    __shared__ float sW1[BK][BN + WPAD];

    const int tid = threadIdx.x;
    const int m0 = blockIdx.x * BM;
    const int n0 = blockIdx.y * BN;

    const int tr = tid / (BN / TN);   // micro-tile row group
    const int tc = tid % (BN / TN);   // micro-tile col group

    float acc[TM][TN];
#pragma unroll
    for (int i = 0; i < TM; ++i)
#pragma unroll
        for (int j = 0; j < TN; ++j) acc[i][j] = 0.f;

    for (int k0 = 0; k0 < Cin; k0 += BK) {
        // --- stage A tiles (BM x BK), transposed into LDS ---
        constexpr int A_LOADS = (BM * BK) / (256 * 4);
#pragma unroll
        for (int l = 0; l < A_LOADS; ++l) {
            int idx = tid + l * 256;
            int row = idx / (BK / 4);
            int c4  = idx - row * (BK / 4);
            int gr  = min(m0 + row, M - 1);          // clamp: safe read, masked at store
            float4 v0 = *(const float4*)&A0[(size_t)gr * Cin + k0 + c4 * 4];
            float4 v1 = *(const float4*)&A1[(size_t)gr * Cin + k0 + c4 * 4];
            sA0[c4 * 4 + 0][row] = v0.x; sA0[c4 * 4 + 1][row] = v0.y;
            sA0[c4 * 4 + 2][row] = v0.z; sA0[c4 * 4 + 3][row] = v0.w;
            sA1[c4 * 4 + 0][row] = v1.x; sA1[c4 * 4 + 1][row] = v1.y;
            sA1[c4 * 4 + 2][row] = v1.z; sA1[c4 * 4 + 3][row] = v1.w;
        }
        // --- stage W tiles (BK x BN) ---
        constexpr int W_LOADS = (BK * BN) / (256 * 4);
#pragma unroll
        for (int l = 0; l < W_LOADS; ++l) {
            int idx = tid + l * 256;
            int row = idx / (BN / 4);
            int c4  = idx - row * (BN / 4);
            float4 w0 = *(const float4*)&W0[(size_t)(k0 + row) * Cout + n0 + c4 * 4];
            float4 w1 = *(const float4*)&W1[(size_t)(k0 + row) * Cout + n0 + c4 * 4];
            *(float4*)&sW0[row][c4 * 4] = w0;
            *(float4*)&sW1[row][c4 * 4] = w1;
        }
        __syncthreads();

#pragma unroll
        for (int k = 0; k < BK; ++k) {
            float a0[TM], a1[TM], w0v[TN], w1v[TN];
#pragma unroll
            for (int i = 0; i < TM; ++i) {
                a0[i] = sA0[k][tr * TM + i];
                a1[i] = sA1[k][tr * TM + i];
            }
#pragma unroll
            for (int j = 0; j < TN; ++j) {
                w0v[j] = sW0[k][tc * TN + j];
                w1v[j] = sW1[k][tc * TN + j];
            }
#pragma unroll
            for (int i = 0; i < TM; ++i)
#pragma unroll
                for (int j = 0; j < TN; ++j)
                    acc[i][j] = fmaf(a0[i], w0v[j], fmaf(a1[i], w1v[j], acc[i][j]));
        }
        __syncthreads();
    }

    // --- epilogue: bias + relu, float4 stores ---
#pragma unroll
    for (int i = 0; i < TM; ++i) {
        int m = m0 + tr * TM + i;
        if (m >= M) continue;
#pragma unroll
        for (int j0 = 0; j0 < TN; j0 += 4) {
            if (TN >= 4) {
                int n = n0 + tc * TN + j0;
                float4 bv = *(const float4*)&bias[n];
                float4 r;
                r.x = acc[i][j0 + 0] + bv.x;
                r.y = acc[i][j0 + 1] + bv.y;
                r.z = acc[i][j0 + 2] + bv.z;
                r.w = acc[i][j0 + 3] + bv.w;
                if (RELU) {
                    r.x = fmaxf(r.x, 0.f); r.y = fmaxf(r.y, 0.f);
                    r.z = fmaxf(r.z, 0.f); r.w = fmaxf(r.w, 0.f);
                }
                *(float4*)&C[(size_t)m * Cout + n] = r;
            } else {
#pragma unroll
                for (int j = j0; j < j0 + 4 && j < TN; ++j) {
                    int n = n0 + tc * TN + j;
                    float v = acc[i][j] + bias[n];
                    if (RELU) v = fmaxf(v, 0.f);
                    C[(size_t)m * Cout + n] = v;
                }
            }
        }
    }
}

// layer-1 linear (Cin=2): trivial K, keep one-thread-per-output
__global__ __launch_bounds__(256) void sage_linear2(const float* __restrict__ agg,
                                                    const float* __restrict__ h,
                                                    const float* __restrict__ Wl,
                                                    const float* __restrict__ bl,
                                                    const float* __restrict__ Wr,
                                                    float* __restrict__ out, int nnodes) {
    constexpr int Cout = 128;
    int t = blockIdx.x * blockDim.x + threadIdx.x;
    if (t >= nnodes * Cout) return;
    int node = t / Cout;
    int c = t - node * Cout;
    float2 a = ((const float2*)agg)[node];
    float2 hh = ((const float2*)h)[node];
    float acc = bl[c];
    acc = fmaf(a.x, Wl[c], acc);
    acc = fmaf(a.y, Wl[Cout + c], acc);
    acc = fmaf(hh.x, Wr[c], acc);
    acc = fmaf(hh.y, Wr[Cout + c], acc);
    out[t] = fmaxf(acc, 0.f);
}

// final projection: h(N x 32) @ W(32x1) + b
__global__ __launch_bounds__(256) void out_proj(const float* __restrict__ h,
                                                const float* __restrict__ W,
                                                const float* __restrict__ b,
                                                float* __restrict__ out, int nnodes) {
    int n = blockIdx.x * blockDim.x + threadIdx.x;
    if (n >= nnodes) return;
    const float4* h4 = (const float4*)(h + (size_t)n * 32);
    float acc = b[0];
#pragma unroll
    for (int k4 = 0; k4 < 8; ++k4) {
        float4 v = h4[k4];
        const float* w = W + k4 * 4;
        acc = fmaf(v.x, w[0], acc);
        acc = fmaf(v.y, w[1], acc);
        acc = fmaf(v.z, w[2], acc);
        acc = fmaf(v.w, w[3], acc);
    }
    out[n] = acc;
}

// ---------------- launch ----------------

extern "C" void kernel_launch(void* const* d_in, const int* in_sizes, int n_in,
                              void* d_out, int out_size, void* d_ws, size_t ws_size,
                              hipStream_t stream) {
    const float* x      = (const float*)d_in[0];
    const int*   ei     = (const int*)d_in[1];   // [2, E]
    const float* Wl1    = (const float*)d_in[3];
    const float* bl1    = (const float*)d_in[4];
    const float* Wr1    = (const float*)d_in[5];
    const float* Wl2    = (const float*)d_in[6];
    const float* bl2    = (const float*)d_in[7];
    const float* Wr2    = (const float*)d_in[8];
    const float* Wl3    = (const float*)d_in[9];
    const float* bl3    = (const float*)d_in[10];
    const float* Wr3    = (const float*)d_in[11];
    const float* Wl4    = (const float*)d_in[12];
    const float* bl4    = (const float*)d_in[13];
    const float* Wr4    = (const float*)d_in[14];
    const float* Wl5    = (const float*)d_in[15];
    const float* bl5    = (const float*)d_in[16];
    const float* Wr5    = (const float*)d_in[17];
    const float* W_out  = (const float*)d_in[18];
    const float* b_out  = (const float*)d_in[19];
    float* out = (float*)d_out;

    const int N = N_NODES, E = N_EDGES;
    const int* e_src = ei;
    const int* e_dst = ei + E;

    size_t off = 0;
    auto carve = [&](size_t bytes) {
        void* p = (char*)d_ws + off;
        off += (bytes + 255) & ~(size_t)255;
        return p;
    };
    int*   counts  = (int*)carve((size_t)N * 4);
    int*   offsets = (int*)carve((size_t)(N + 1) * 4);
    int*   cursor  = (int*)carve((size_t)N * 4);
    float* inv_deg = (float*)carve((size_t)N * 4);
    int*   ssrc    = (int*)carve((size_t)E * 4);
    float* agg     = (float*)carve((size_t)N * 128 * 4);
    float* bufA    = (float*)carve((size_t)N * 128 * 4);
    float* bufB    = (float*)carve((size_t)N * 128 * 4);

    // --- CSR build ---
    hipMemsetAsync(counts, 0, (size_t)N * 4, stream);
    count_deg<<<(E + 255) / 256, 256, 0, stream>>>(e_dst, counts, E);
    scan_offsets<<<1, 1024, 0, stream>>>(counts, offsets, inv_deg, N);
    hipMemcpyAsync(cursor, offsets, (size_t)N * 4, hipMemcpyDeviceToDevice, stream);
    fill_csr<<<(E + 255) / 256, 256, 0, stream>>>(e_src, e_dst, cursor, ssrc, E);

    // --- layer 1: 2 -> 128 ---
    aggregate2<<<(N + 255) / 256, 256, 0, stream>>>(x, offsets, ssrc, inv_deg, agg, N);
    sage_linear2<<<(N * 128 + 255) / 256, 256, 0, stream>>>(agg, x, Wl1, bl1, Wr1, bufA, N);

    // --- layer 2: 128 -> 128 ---  BM=64,BN=64, grid (1563, 2)
    aggregate4<128><<<(N * 32 + 255) / 256, 256, 0, stream>>>(bufA, offsets, ssrc, inv_deg, agg, N);
    {
        dim3 g((N + 63) / 64, 128 / 64);
        sage_gemm<128, 128, 64, 64, true><<<g, 256, 0, stream>>>(agg, bufA, Wl2, bl2, Wr2, bufB, N);
    }

    // --- layer 3: 128 -> 32 ---  BM=128,BN=32
    aggregate4<128><<<(N * 32 + 255) / 256, 256, 0, stream>>>(bufB, offsets, ssrc, inv_deg, agg, N);
    {
        dim3 g((N + 127) / 128, 1);
        sage_gemm<128, 32, 128, 32, true><<<g, 256, 0, stream>>>(agg, bufB, Wl3, bl3, Wr3, bufA, N);
    }

    // --- layer 4: 32 -> 32 ---
    aggregate4<32><<<(N * 8 + 255) / 256, 256, 0, stream>>>(bufA, offsets, ssrc, inv_deg, agg, N);
    {
        dim3 g((N + 127) / 128, 1);
        sage_gemm<32, 32, 128, 32, true><<<g, 256, 0, stream>>>(agg, bufA, Wl4, bl4, Wr4, bufB, N);
    }

    // --- layer 5: 32 -> 32 ---
    aggregate4<32><<<(N * 8 + 255) / 256, 256, 0, stream>>>(bufB, offsets, ssrc, inv_deg, agg, N);
    {
        dim3 g((N + 127) / 128, 1);
        sage_gemm<32, 32, 128, 32, true><<<g, 256, 0, stream>>>(agg, bufB, Wl5, bl5, Wr5, bufA, N);
    }

    // --- output projection ---
    out_proj<<<(N + 255) / 256, 256, 0, stream>>>(bufA, W_out, b_out, out, N);
}

// Round 3
// 1026.814 us; speedup vs baseline: 2.1869x; 1.5702x over previous
//
#include <hip/hip_runtime.h>
#include <hip/hip_bf16.h>

#define N_NODES 100000
#define N_EDGES 1600000

// ---------------- CSR build ----------------

__global__ __launch_bounds__(256) void count_deg(const int* __restrict__ dst,
                                                 int* __restrict__ counts, int ne) {
    int e = blockIdx.x * blockDim.x + threadIdx.x;
    if (e < ne) atomicAdd(&counts[dst[e]], 1);
}

__global__ __launch_bounds__(1024) void scan_offsets(const int* __restrict__ counts,
                                                     int* __restrict__ offsets,
                                                     float* __restrict__ inv_deg, int n) {
    __shared__ int sums[1024];
    int tid = threadIdx.x;
    int chunk = (n + 1023) >> 10;
    int b = tid * chunk;
    int e = min(b + chunk, n);
    int s = 0;
    for (int i = b; i < e; ++i) s += counts[i];
    sums[tid] = s;
    __syncthreads();
    for (int off = 1; off < 1024; off <<= 1) {
        int v = (tid >= off) ? sums[tid - off] : 0;
        __syncthreads();
        sums[tid] += v;
        __syncthreads();
    }
    int run = (tid == 0) ? 0 : sums[tid - 1];
    for (int i = b; i < e; ++i) {
        offsets[i] = run;
        int c = counts[i];
        inv_deg[i] = 1.0f / (float)max(c, 1);
        run += c;
    }
    if (tid == 1023) offsets[n] = sums[1023];
}

__global__ __launch_bounds__(256) void fill_csr(const int* __restrict__ src,
                                                const int* __restrict__ dst,
                                                int* __restrict__ cursor,
                                                int* __restrict__ sorted_src, int ne) {
    int e = blockIdx.x * blockDim.x + threadIdx.x;
    if (e < ne) {
        int p = atomicAdd(&cursor[dst[e]], 1);
        sorted_src[p] = src[e];
    }
}

// ---------------- aggregation ----------------

template <int Cin>
__global__ __launch_bounds__(256) void aggregate4(const float* __restrict__ h,
                                                  const int* __restrict__ offs,
                                                  const int* __restrict__ ssrc,
                                                  const float* __restrict__ inv_deg,
                                                  float* __restrict__ agg, int nnodes) {
    constexpr int C4 = Cin / 4;
    int t = blockIdx.x * blockDim.x + threadIdx.x;
    if (t >= nnodes * C4) return;
    int node = t / C4;
    int c = t - node * C4;
    int b = offs[node], e = offs[node + 1];
    const float4* __restrict__ h4 = (const float4*)h;
    float4 acc = make_float4(0.f, 0.f, 0.f, 0.f);
    for (int i = b; i < e; ++i) {
        float4 v = h4[(size_t)ssrc[i] * C4 + c];
        acc.x += v.x; acc.y += v.y; acc.z += v.z; acc.w += v.w;
    }
    float s = inv_deg[node];
    acc.x *= s; acc.y *= s; acc.z *= s; acc.w *= s;
    ((float4*)agg)[t] = acc;
}

__global__ __launch_bounds__(256) void aggregate2(const float* __restrict__ h,
                                                  const int* __restrict__ offs,
                                                  const int* __restrict__ ssrc,
                                                  const float* __restrict__ inv_deg,
                                                  float* __restrict__ agg, int nnodes) {
    int node = blockIdx.x * blockDim.x + threadIdx.x;
    if (node >= nnodes) return;
    int b = offs[node], e = offs[node + 1];
    const float2* __restrict__ h2 = (const float2*)h;
    float2 acc = make_float2(0.f, 0.f);
    for (int i = b; i < e; ++i) {
        float2 v = h2[ssrc[i]];
        acc.x += v.x; acc.y += v.y;
    }
    float s = inv_deg[node];
    acc.x *= s; acc.y *= s;
    ((float2*)agg)[node] = acc;
}

// ---------------- layer-2 GEMM: C = relu(A0@W0 + b + A1@W1), Cin=Cout=128 ----
// BM=128, BN=128, BK=8, 256 threads, 8x8 micro-tile, single shared accumulator.

__global__ __launch_bounds__(256) void gemm_l2(const float* __restrict__ A0,
                                               const float* __restrict__ A1,
                                               const float* __restrict__ W0,
                                               const float* __restrict__ bias,
                                               const float* __restrict__ W1,
                                               float* __restrict__ C, int M) {
    constexpr int CIN = 128, COUT = 128, BM = 128, BN = 128, BK = 8;
    __shared__ float sA0[BK][BM + 4];
    __shared__ float sA1[BK][BM + 4];
    __shared__ float sW0[BK][BN + 4];
    __shared__ float sW1[BK][BN + 4];

    const int tid = threadIdx.x;
    const int m0 = blockIdx.x * BM;
    const int tr = tid >> 4;          // 0..15 -> rows tr*8..tr*8+7
    const int tc = tid & 15;          // 0..15 -> cols tc*8..tc*8+7

    float acc[8][8];
#pragma unroll
    for (int i = 0; i < 8; ++i)
#pragma unroll
        for (int j = 0; j < 8; ++j) acc[i][j] = 0.f;

    // staging indices (1 float4 per thread per array per tile)
    const int arow = tid >> 1;            // 0..127
    const int ac4  = tid & 1;             // k-offset group
    const int wrow = tid >> 5;            // 0..7
    const int wc4  = tid & 31;            // 0..31

    const int gr = min(m0 + arow, M - 1);

    for (int k0 = 0; k0 < CIN; k0 += BK) {
        float4 v0 = *(const float4*)&A0[(size_t)gr * CIN + k0 + ac4 * 4];
        float4 v1 = *(const float4*)&A1[(size_t)gr * CIN + k0 + ac4 * 4];
        float4 w0 = *(const float4*)&W0[(size_t)(k0 + wrow) * COUT + wc4 * 4];
        float4 w1 = *(const float4*)&W1[(size_t)(k0 + wrow) * COUT + wc4 * 4];
        sA0[ac4 * 4 + 0][arow] = v0.x; sA0[ac4 * 4 + 1][arow] = v0.y;
        sA0[ac4 * 4 + 2][arow] = v0.z; sA0[ac4 * 4 + 3][arow] = v0.w;
        sA1[ac4 * 4 + 0][arow] = v1.x; sA1[ac4 * 4 + 1][arow] = v1.y;
        sA1[ac4 * 4 + 2][arow] = v1.z; sA1[ac4 * 4 + 3][arow] = v1.w;
        *(float4*)&sW0[wrow][wc4 * 4] = w0;
        *(float4*)&sW1[wrow][wc4 * 4] = w1;
        __syncthreads();

#pragma unroll
        for (int k = 0; k < BK; ++k) {
            float4 a0l = *(const float4*)&sA0[k][tr * 8];
            float4 a0h = *(const float4*)&sA0[k][tr * 8 + 4];
            float4 a1l = *(const float4*)&sA1[k][tr * 8];
            float4 a1h = *(const float4*)&sA1[k][tr * 8 + 4];
            float4 w0l = *(const float4*)&sW0[k][tc * 8];
            float4 w0h = *(const float4*)&sW0[k][tc * 8 + 4];
            float4 w1l = *(const float4*)&sW1[k][tc * 8];
            float4 w1h = *(const float4*)&sW1[k][tc * 8 + 4];
            float a0[8] = {a0l.x, a0l.y, a0l.z, a0l.w, a0h.x, a0h.y, a0h.z, a0h.w};
            float a1[8] = {a1l.x, a1l.y, a1l.z, a1l.w, a1h.x, a1h.y, a1h.z, a1h.w};
            float w0v[8] = {w0l.x, w0l.y, w0l.z, w0l.w, w0h.x, w0h.y, w0h.z, w0h.w};
            float w1v[8] = {w1l.x, w1l.y, w1l.z, w1l.w, w1h.x, w1h.y, w1h.z, w1h.w};
#pragma unroll
            for (int i = 0; i < 8; ++i)
#pragma unroll
                for (int j = 0; j < 8; ++j)
                    acc[i][j] = fmaf(a0[i], w0v[j], fmaf(a1[i], w1v[j], acc[i][j]));
        }
        __syncthreads();
    }

#pragma unroll
    for (int i = 0; i < 8; ++i) {
        int m = m0 + tr * 8 + i;
        if (m >= M) continue;
#pragma unroll
        for (int j0 = 0; j0 < 8; j0 += 4) {
            int n = tc * 8 + j0;
            float4 bv = *(const float4*)&bias[n];
            float4 r;
            r.x = fmaxf(acc[i][j0 + 0] + bv.x, 0.f);
            r.y = fmaxf(acc[i][j0 + 1] + bv.y, 0.f);
            r.z = fmaxf(acc[i][j0 + 2] + bv.z, 0.f);
            r.w = fmaxf(acc[i][j0 + 3] + bv.w, 0.f);
            *(float4*)&C[(size_t)m * COUT + n] = r;
        }
    }
}

// ---------------- Cout=32 GEMM: BM=128, BN=32, BK=16, 4x4 micro-tile --------

template <int Cin>
__global__ __launch_bounds__(256) void gemm_n32(const float* __restrict__ A0,
                                                const float* __restrict__ A1,
                                                const float* __restrict__ W0,
                                                const float* __restrict__ bias,
                                                const float* __restrict__ W1,
                                                float* __restrict__ C, int M) {
    constexpr int COUT = 32, BM = 128, BN = 32, BK = 16;
    __shared__ float sA0[BK][BM + 4];
    __shared__ float sA1[BK][BM + 4];
    __shared__ float sW0[BK][BN + 4];
    __shared__ float sW1[BK][BN + 4];

    const int tid = threadIdx.x;
    const int m0 = blockIdx.x * BM;
    const int tr = tid >> 3;          // 0..31 -> rows tr*4
    const int tc = tid & 7;           // 0..7  -> cols tc*4

    float acc[4][4];
#pragma unroll
    for (int i = 0; i < 4; ++i)
#pragma unroll
        for (int j = 0; j < 4; ++j) acc[i][j] = 0.f;

    // A staging: BM*BK = 2048 floats = 512 float4; 256 threads x 2
    // W staging: BK*BN = 512 floats = 128 float4; threads 0..127
    const int wrow = tid >> 3;        // 0..15 (only tid<128 used)
    const int wc4  = tid & 7;

    for (int k0 = 0; k0 < Cin; k0 += BK) {
#pragma unroll
        for (int l = 0; l < 2; ++l) {
            int idx = tid + l * 256;
            int row = idx >> 2;           // 0..127
            int c4  = idx & 3;            // k group
            int gr  = min(m0 + row, M - 1);
            float4 v0 = *(const float4*)&A0[(size_t)gr * Cin + k0 + c4 * 4];
            float4 v1 = *(const float4*)&A1[(size_t)gr * Cin + k0 + c4 * 4];
            sA0[c4 * 4 + 0][row] = v0.x; sA0[c4 * 4 + 1][row] = v0.y;
            sA0[c4 * 4 + 2][row] = v0.z; sA0[c4 * 4 + 3][row] = v0.w;
            sA1[c4 * 4 + 0][row] = v1.x; sA1[c4 * 4 + 1][row] = v1.y;
            sA1[c4 * 4 + 2][row] = v1.z; sA1[c4 * 4 + 3][row] = v1.w;
        }
        if (tid < 128) {
            float4 w0 = *(const float4*)&W0[(size_t)(k0 + wrow) * COUT + wc4 * 4];
            float4 w1 = *(const float4*)&W1[(size_t)(k0 + wrow) * COUT + wc4 * 4];
            *(float4*)&sW0[wrow][wc4 * 4] = w0;
            *(float4*)&sW1[wrow][wc4 * 4] = w1;
        }
        __syncthreads();

#pragma unroll
        for (int k = 0; k < BK; ++k) {
            float4 a0 = *(const float4*)&sA0[k][tr * 4];
            float4 a1 = *(const float4*)&sA1[k][tr * 4];
            float4 w0 = *(const float4*)&sW0[k][tc * 4];
            float4 w1 = *(const float4*)&sW1[k][tc * 4];
            float av0[4] = {a0.x, a0.y, a0.z, a0.w};
            float av1[4] = {a1.x, a1.y, a1.z, a1.w};
            float wv0[4] = {w0.x, w0.y, w0.z, w0.w};
            float wv1[4] = {w1.x, w1.y, w1.z, w1.w};
#pragma unroll
            for (int i = 0; i < 4; ++i)
#pragma unroll
                for (int j = 0; j < 4; ++j)
                    acc[i][j] = fmaf(av0[i], wv0[j], fmaf(av1[i], wv1[j], acc[i][j]));
        }
        __syncthreads();
    }

#pragma unroll
    for (int i = 0; i < 4; ++i) {
        int m = m0 + tr * 4 + i;
        if (m >= M) continue;
        int n = tc * 4;
        float4 bv = *(const float4*)&bias[n];
        float4 r;
        r.x = fmaxf(acc[i][0] + bv.x, 0.f);
        r.y = fmaxf(acc[i][1] + bv.y, 0.f);
        r.z = fmaxf(acc[i][2] + bv.z, 0.f);
        r.w = fmaxf(acc[i][3] + bv.w, 0.f);
        *(float4*)&C[(size_t)m * COUT + n] = r;
    }
}

// layer-1 linear (Cin=2)
__global__ __launch_bounds__(256) void sage_linear2(const float* __restrict__ agg,
                                                    const float* __restrict__ h,
                                                    const float* __restrict__ Wl,
                                                    const float* __restrict__ bl,
                                                    const float* __restrict__ Wr,
                                                    float* __restrict__ out, int nnodes) {
    constexpr int Cout = 128;
    int t = blockIdx.x * blockDim.x + threadIdx.x;
    if (t >= nnodes * Cout) return;
    int node = t / Cout;
    int c = t - node * Cout;
    float2 a = ((const float2*)agg)[node];
    float2 hh = ((const float2*)h)[node];
    float acc = bl[c];
    acc = fmaf(a.x, Wl[c], acc);
    acc = fmaf(a.y, Wl[Cout + c], acc);
    acc = fmaf(hh.x, Wr[c], acc);
    acc = fmaf(hh.y, Wr[Cout + c], acc);
    out[t] = fmaxf(acc, 0.f);
}

// final projection: h(N x 32) @ W(32x1) + b
__global__ __launch_bounds__(256) void out_proj(const float* __restrict__ h,
                                                const float* __restrict__ W,
                                                const float* __restrict__ b,
                                                float* __restrict__ out, int nnodes) {
    int n = blockIdx.x * blockDim.x + threadIdx.x;
    if (n >= nnodes) return;
    const float4* h4 = (const float4*)(h + (size_t)n * 32);
    float acc = b[0];
#pragma unroll
    for (int k4 = 0; k4 < 8; ++k4) {
        float4 v = h4[k4];
        const float* w = W + k4 * 4;
        acc = fmaf(v.x, w[0], acc);
        acc = fmaf(v.y, w[1], acc);
        acc = fmaf(v.z, w[2], acc);
        acc = fmaf(v.w, w[3], acc);
    }
    out[n] = acc;
}

// ---------------- launch ----------------

extern "C" void kernel_launch(void* const* d_in, const int* in_sizes, int n_in,
                              void* d_out, int out_size, void* d_ws, size_t ws_size,
                              hipStream_t stream) {
    const float* x      = (const float*)d_in[0];
    const int*   ei     = (const int*)d_in[1];
    const float* Wl1    = (const float*)d_in[3];
    const float* bl1    = (const float*)d_in[4];
    const float* Wr1    = (const float*)d_in[5];
    const float* Wl2    = (const float*)d_in[6];
    const float* bl2    = (const float*)d_in[7];
    const float* Wr2    = (const float*)d_in[8];
    const float* Wl3    = (const float*)d_in[9];
    const float* bl3    = (const float*)d_in[10];
    const float* Wr3    = (const float*)d_in[11];
    const float* Wl4    = (const float*)d_in[12];
    const float* bl4    = (const float*)d_in[13];
    const float* Wr4    = (const float*)d_in[14];
    const float* Wl5    = (const float*)d_in[15];
    const float* bl5    = (const float*)d_in[16];
    const float* Wr5    = (const float*)d_in[17];
    const float* W_out  = (const float*)d_in[18];
    const float* b_out  = (const float*)d_in[19];
    float* out = (float*)d_out;

    const int N = N_NODES, E = N_EDGES;
    const int* e_src = ei;
    const int* e_dst = ei + E;

    size_t off = 0;
    auto carve = [&](size_t bytes) {
        void* p = (char*)d_ws + off;
        off += (bytes + 255) & ~(size_t)255;
        return p;
    };
    int*   counts  = (int*)carve((size_t)N * 4);
    int*   offsets = (int*)carve((size_t)(N + 1) * 4);
    int*   cursor  = (int*)carve((size_t)N * 4);
    float* inv_deg = (float*)carve((size_t)N * 4);
    int*   ssrc    = (int*)carve((size_t)E * 4);
    float* agg     = (float*)carve((size_t)N * 128 * 4);
    float* bufA    = (float*)carve((size_t)N * 128 * 4);
    float* bufB    = (float*)carve((size_t)N * 128 * 4);

    // --- CSR build ---
    hipMemsetAsync(counts, 0, (size_t)N * 4, stream);
    count_deg<<<(E + 255) / 256, 256, 0, stream>>>(e_dst, counts, E);
    scan_offsets<<<1, 1024, 0, stream>>>(counts, offsets, inv_deg, N);
    hipMemcpyAsync(cursor, offsets, (size_t)N * 4, hipMemcpyDeviceToDevice, stream);
    fill_csr<<<(E + 255) / 256, 256, 0, stream>>>(e_src, e_dst, cursor, ssrc, E);

    const int gemm_grid = (N + 127) / 128;

    // --- layer 1: 2 -> 128 ---
    aggregate2<<<(N + 255) / 256, 256, 0, stream>>>(x, offsets, ssrc, inv_deg, agg, N);
    sage_linear2<<<(N * 128 + 255) / 256, 256, 0, stream>>>(agg, x, Wl1, bl1, Wr1, bufA, N);

    // --- layer 2: 128 -> 128 ---
    aggregate4<128><<<(N * 32 + 255) / 256, 256, 0, stream>>>(bufA, offsets, ssrc, inv_deg, agg, N);
    gemm_l2<<<gemm_grid, 256, 0, stream>>>(agg, bufA, Wl2, bl2, Wr2, bufB, N);

    // --- layer 3: 128 -> 32 ---
    aggregate4<128><<<(N * 32 + 255) / 256, 256, 0, stream>>>(bufB, offsets, ssrc, inv_deg, agg, N);
    gemm_n32<128><<<gemm_grid, 256, 0, stream>>>(agg, bufB, Wl3, bl3, Wr3, bufA, N);

    // --- layer 4: 32 -> 32 ---
    aggregate4<32><<<(N * 8 + 255) / 256, 256, 0, stream>>>(bufA, offsets, ssrc, inv_deg, agg, N);
    gemm_n32<32><<<gemm_grid, 256, 0, stream>>>(agg, bufA, Wl4, bl4, Wr4, bufB, N);

    // --- layer 5: 32 -> 32 ---
    aggregate4<32><<<(N * 8 + 255) / 256, 256, 0, stream>>>(bufB, offsets, ssrc, inv_deg, agg, N);
    gemm_n32<32><<<gemm_grid, 256, 0, stream>>>(agg, bufB, Wl5, bl5, Wr5, bufA, N);

    // --- output projection ---
    out_proj<<<(N + 255) / 256, 256, 0, stream>>>(bufA, W_out, b_out, out, N);
}

// Round 4
// 810.459 us; speedup vs baseline: 2.7708x; 1.2670x over previous
//
#include <hip/hip_runtime.h>
#include <hip/hip_bf16.h>

#define N_NODES 100000
#define N_EDGES 1600000

// ---------------- CSR build ----------------

__global__ __launch_bounds__(256) void count_deg(const int* __restrict__ dst,
                                                 int* __restrict__ counts, int ne) {
    int e = blockIdx.x * blockDim.x + threadIdx.x;
    if (e < ne) atomicAdd(&counts[dst[e]], 1);
}

// phase 1: per-block (256-wide) sum of counts
__global__ __launch_bounds__(256) void block_sums(const int* __restrict__ counts,
                                                  int* __restrict__ bsum, int n) {
    int i = blockIdx.x * 256 + threadIdx.x;
    int v = (i < n) ? counts[i] : 0;
#pragma unroll
    for (int off = 32; off > 0; off >>= 1) v += __shfl_down(v, off, 64);
    __shared__ int red[4];
    if ((threadIdx.x & 63) == 0) red[threadIdx.x >> 6] = v;
    __syncthreads();
    if (threadIdx.x == 0) bsum[blockIdx.x] = red[0] + red[1] + red[2] + red[3];
}

// phase 2: single small block scans the block sums (nblocks <= 512)
__global__ __launch_bounds__(512) void scan_bsums(int* __restrict__ bsum,
                                                  int* __restrict__ offsets,
                                                  int nblocks, int n) {
    __shared__ int s[512];
    int tid = threadIdx.x;
    int v = (tid < nblocks) ? bsum[tid] : 0;
    s[tid] = v;
    __syncthreads();
    for (int off = 1; off < 512; off <<= 1) {
        int t = (tid >= off) ? s[tid - off] : 0;
        __syncthreads();
        s[tid] += t;
        __syncthreads();
    }
    if (tid < nblocks) bsum[tid] = s[tid] - v;   // exclusive base
    if (tid == 511) offsets[n] = s[511];
}

// phase 3: per-block exclusive scan + base -> offsets, cursor, inv_deg
__global__ __launch_bounds__(256) void emit_offsets(const int* __restrict__ counts,
                                                    const int* __restrict__ bsum,
                                                    int* __restrict__ offsets,
                                                    int* __restrict__ cursor,
                                                    float* __restrict__ inv_deg, int n) {
    __shared__ int s[256];
    int tid = threadIdx.x;
    int i = blockIdx.x * 256 + tid;
    int c = (i < n) ? counts[i] : 0;
    s[tid] = c;
    __syncthreads();
    for (int off = 1; off < 256; off <<= 1) {
        int t = (tid >= off) ? s[tid - off] : 0;
        __syncthreads();
        s[tid] += t;
        __syncthreads();
    }
    if (i < n) {
        int excl = s[tid] - c + bsum[blockIdx.x];
        offsets[i] = excl;
        cursor[i] = excl;
        inv_deg[i] = 1.0f / (float)max(c, 1);
    }
}

__global__ __launch_bounds__(256) void fill_csr(const int* __restrict__ src,
                                                const int* __restrict__ dst,
                                                int* __restrict__ cursor,
                                                int* __restrict__ sorted_src, int ne) {
    int e = blockIdx.x * blockDim.x + threadIdx.x;
    if (e < ne) {
        int p = atomicAdd(&cursor[dst[e]], 1);
        sorted_src[p] = src[e];
    }
}

// ---------------- aggregation ----------------

template <int Cin>
__global__ __launch_bounds__(256) void aggregate4(const float* __restrict__ h,
                                                  const int* __restrict__ offs,
                                                  const int* __restrict__ ssrc,
                                                  const float* __restrict__ inv_deg,
                                                  float* __restrict__ agg, int nnodes) {
    constexpr int C4 = Cin / 4;
    int t = blockIdx.x * blockDim.x + threadIdx.x;
    if (t >= nnodes * C4) return;
    int node = t / C4;
    int c = t - node * C4;
    int b = offs[node], e = offs[node + 1];
    const float4* __restrict__ h4 = (const float4*)h;
    float4 acc = make_float4(0.f, 0.f, 0.f, 0.f);
    for (int i = b; i < e; ++i) {
        float4 v = h4[(size_t)ssrc[i] * C4 + c];
        acc.x += v.x; acc.y += v.y; acc.z += v.z; acc.w += v.w;
    }
    float s = inv_deg[node];
    acc.x *= s; acc.y *= s; acc.z *= s; acc.w *= s;
    ((float4*)agg)[t] = acc;
}

__global__ __launch_bounds__(256) void aggregate2(const float* __restrict__ h,
                                                  const int* __restrict__ offs,
                                                  const int* __restrict__ ssrc,
                                                  const float* __restrict__ inv_deg,
                                                  float* __restrict__ agg, int nnodes) {
    int node = blockIdx.x * blockDim.x + threadIdx.x;
    if (node >= nnodes) return;
    int b = offs[node], e = offs[node + 1];
    const float2* __restrict__ h2 = (const float2*)h;
    float2 acc = make_float2(0.f, 0.f);
    for (int i = b; i < e; ++i) {
        float2 v = h2[ssrc[i]];
        acc.x += v.x; acc.y += v.y;
    }
    float s = inv_deg[node];
    acc.x *= s; acc.y *= s;
    ((float2*)agg)[node] = acc;
}

// ---------------- layer-2 GEMM: C = relu(A0@W0 + b + A1@W1), Cin=Cout=128 ----

__global__ __launch_bounds__(256) void gemm_l2(const float* __restrict__ A0,
                                               const float* __restrict__ A1,
                                               const float* __restrict__ W0,
                                               const float* __restrict__ bias,
                                               const float* __restrict__ W1,
                                               float* __restrict__ C, int M) {
    constexpr int CIN = 128, COUT = 128, BM = 128, BN = 128, BK = 8;
    __shared__ float sA0[BK][BM + 4];
    __shared__ float sA1[BK][BM + 4];
    __shared__ float sW0[BK][BN + 4];
    __shared__ float sW1[BK][BN + 4];

    const int tid = threadIdx.x;
    const int m0 = blockIdx.x * BM;
    const int tr = tid >> 4;
    const int tc = tid & 15;

    float acc[8][8];
#pragma unroll
    for (int i = 0; i < 8; ++i)
#pragma unroll
        for (int j = 0; j < 8; ++j) acc[i][j] = 0.f;

    const int arow = tid >> 1;
    const int ac4  = tid & 1;
    const int wrow = tid >> 5;
    const int wc4  = tid & 31;

    const int gr = min(m0 + arow, M - 1);

    for (int k0 = 0; k0 < CIN; k0 += BK) {
        float4 v0 = *(const float4*)&A0[(size_t)gr * CIN + k0 + ac4 * 4];
        float4 v1 = *(const float4*)&A1[(size_t)gr * CIN + k0 + ac4 * 4];
        float4 w0 = *(const float4*)&W0[(size_t)(k0 + wrow) * COUT + wc4 * 4];
        float4 w1 = *(const float4*)&W1[(size_t)(k0 + wrow) * COUT + wc4 * 4];
        sA0[ac4 * 4 + 0][arow] = v0.x; sA0[ac4 * 4 + 1][arow] = v0.y;
        sA0[ac4 * 4 + 2][arow] = v0.z; sA0[ac4 * 4 + 3][arow] = v0.w;
        sA1[ac4 * 4 + 0][arow] = v1.x; sA1[ac4 * 4 + 1][arow] = v1.y;
        sA1[ac4 * 4 + 2][arow] = v1.z; sA1[ac4 * 4 + 3][arow] = v1.w;
        *(float4*)&sW0[wrow][wc4 * 4] = w0;
        *(float4*)&sW1[wrow][wc4 * 4] = w1;
        __syncthreads();

#pragma unroll
        for (int k = 0; k < BK; ++k) {
            float4 a0l = *(const float4*)&sA0[k][tr * 8];
            float4 a0h = *(const float4*)&sA0[k][tr * 8 + 4];
            float4 a1l = *(const float4*)&sA1[k][tr * 8];
            float4 a1h = *(const float4*)&sA1[k][tr * 8 + 4];
            float4 w0l = *(const float4*)&sW0[k][tc * 8];
            float4 w0h = *(const float4*)&sW0[k][tc * 8 + 4];
            float4 w1l = *(const float4*)&sW1[k][tc * 8];
            float4 w1h = *(const float4*)&sW1[k][tc * 8 + 4];
            float a0[8] = {a0l.x, a0l.y, a0l.z, a0l.w, a0h.x, a0h.y, a0h.z, a0h.w};
            float a1[8] = {a1l.x, a1l.y, a1l.z, a1l.w, a1h.x, a1h.y, a1h.z, a1h.w};
            float w0v[8] = {w0l.x, w0l.y, w0l.z, w0l.w, w0h.x, w0h.y, w0h.z, w0h.w};
            float w1v[8] = {w1l.x, w1l.y, w1l.z, w1l.w, w1h.x, w1h.y, w1h.z, w1h.w};
#pragma unroll
            for (int i = 0; i < 8; ++i)
#pragma unroll
                for (int j = 0; j < 8; ++j)
                    acc[i][j] = fmaf(a0[i], w0v[j], fmaf(a1[i], w1v[j], acc[i][j]));
        }
        __syncthreads();
    }

#pragma unroll
    for (int i = 0; i < 8; ++i) {
        int m = m0 + tr * 8 + i;
        if (m >= M) continue;
#pragma unroll
        for (int j0 = 0; j0 < 8; j0 += 4) {
            int n = tc * 8 + j0;
            float4 bv = *(const float4*)&bias[n];
            float4 r;
            r.x = fmaxf(acc[i][j0 + 0] + bv.x, 0.f);
            r.y = fmaxf(acc[i][j0 + 1] + bv.y, 0.f);
            r.z = fmaxf(acc[i][j0 + 2] + bv.z, 0.f);
            r.w = fmaxf(acc[i][j0 + 3] + bv.w, 0.f);
            *(float4*)&C[(size_t)m * COUT + n] = r;
        }
    }
}

// ---------------- Cout=32 GEMM: BM=128, BN=32, BK=16, 4x4 micro-tile --------

template <int Cin>
__global__ __launch_bounds__(256) void gemm_n32(const float* __restrict__ A0,
                                                const float* __restrict__ A1,
                                                const float* __restrict__ W0,
                                                const float* __restrict__ bias,
                                                const float* __restrict__ W1,
                                                float* __restrict__ C, int M) {
    constexpr int COUT = 32, BM = 128, BN = 32, BK = 16;
    __shared__ float sA0[BK][BM + 4];
    __shared__ float sA1[BK][BM + 4];
    __shared__ float sW0[BK][BN + 4];
    __shared__ float sW1[BK][BN + 4];

    const int tid = threadIdx.x;
    const int m0 = blockIdx.x * BM;
    const int tr = tid >> 3;
    const int tc = tid & 7;

    float acc[4][4];
#pragma unroll
    for (int i = 0; i < 4; ++i)
#pragma unroll
        for (int j = 0; j < 4; ++j) acc[i][j] = 0.f;

    const int wrow = tid >> 3;
    const int wc4  = tid & 7;

    for (int k0 = 0; k0 < Cin; k0 += BK) {
#pragma unroll
        for (int l = 0; l < 2; ++l) {
            int idx = tid + l * 256;
            int row = idx >> 2;
            int c4  = idx & 3;
            int gr  = min(m0 + row, M - 1);
            float4 v0 = *(const float4*)&A0[(size_t)gr * Cin + k0 + c4 * 4];
            float4 v1 = *(const float4*)&A1[(size_t)gr * Cin + k0 + c4 * 4];
            sA0[c4 * 4 + 0][row] = v0.x; sA0[c4 * 4 + 1][row] = v0.y;
            sA0[c4 * 4 + 2][row] = v0.z; sA0[c4 * 4 + 3][row] = v0.w;
            sA1[c4 * 4 + 0][row] = v1.x; sA1[c4 * 4 + 1][row] = v1.y;
            sA1[c4 * 4 + 2][row] = v1.z; sA1[c4 * 4 + 3][row] = v1.w;
        }
        if (tid < 128) {
            float4 w0 = *(const float4*)&W0[(size_t)(k0 + wrow) * COUT + wc4 * 4];
            float4 w1 = *(const float4*)&W1[(size_t)(k0 + wrow) * COUT + wc4 * 4];
            *(float4*)&sW0[wrow][wc4 * 4] = w0;
            *(float4*)&sW1[wrow][wc4 * 4] = w1;
        }
        __syncthreads();

#pragma unroll
        for (int k = 0; k < BK; ++k) {
            float4 a0 = *(const float4*)&sA0[k][tr * 4];
            float4 a1 = *(const float4*)&sA1[k][tr * 4];
            float4 w0 = *(const float4*)&sW0[k][tc * 4];
            float4 w1 = *(const float4*)&sW1[k][tc * 4];
            float av0[4] = {a0.x, a0.y, a0.z, a0.w};
            float av1[4] = {a1.x, a1.y, a1.z, a1.w};
            float wv0[4] = {w0.x, w0.y, w0.z, w0.w};
            float wv1[4] = {w1.x, w1.y, w1.z, w1.w};
#pragma unroll
            for (int i = 0; i < 4; ++i)
#pragma unroll
                for (int j = 0; j < 4; ++j)
                    acc[i][j] = fmaf(av0[i], wv0[j], fmaf(av1[i], wv1[j], acc[i][j]));
        }
        __syncthreads();
    }

#pragma unroll
    for (int i = 0; i < 4; ++i) {
        int m = m0 + tr * 4 + i;
        if (m >= M) continue;
        int n = tc * 4;
        float4 bv = *(const float4*)&bias[n];
        float4 r;
        r.x = fmaxf(acc[i][0] + bv.x, 0.f);
        r.y = fmaxf(acc[i][1] + bv.y, 0.f);
        r.z = fmaxf(acc[i][2] + bv.z, 0.f);
        r.w = fmaxf(acc[i][3] + bv.w, 0.f);
        *(float4*)&C[(size_t)m * COUT + n] = r;
    }
}

// layer-1 linear (Cin=2)
__global__ __launch_bounds__(256) void sage_linear2(const float* __restrict__ agg,
                                                    const float* __restrict__ h,
                                                    const float* __restrict__ Wl,
                                                    const float* __restrict__ bl,
                                                    const float* __restrict__ Wr,
                                                    float* __restrict__ out, int nnodes) {
    constexpr int Cout = 128;
    int t = blockIdx.x * blockDim.x + threadIdx.x;
    if (t >= nnodes * Cout) return;
    int node = t / Cout;
    int c = t - node * Cout;
    float2 a = ((const float2*)agg)[node];
    float2 hh = ((const float2*)h)[node];
    float acc = bl[c];
    acc = fmaf(a.x, Wl[c], acc);
    acc = fmaf(a.y, Wl[Cout + c], acc);
    acc = fmaf(hh.x, Wr[c], acc);
    acc = fmaf(hh.y, Wr[Cout + c], acc);
    out[t] = fmaxf(acc, 0.f);
}

// final projection
__global__ __launch_bounds__(256) void out_proj(const float* __restrict__ h,
                                                const float* __restrict__ W,
                                                const float* __restrict__ b,
                                                float* __restrict__ out, int nnodes) {
    int n = blockIdx.x * blockDim.x + threadIdx.x;
    if (n >= nnodes) return;
    const float4* h4 = (const float4*)(h + (size_t)n * 32);
    float acc = b[0];
#pragma unroll
    for (int k4 = 0; k4 < 8; ++k4) {
        float4 v = h4[k4];
        const float* w = W + k4 * 4;
        acc = fmaf(v.x, w[0], acc);
        acc = fmaf(v.y, w[1], acc);
        acc = fmaf(v.z, w[2], acc);
        acc = fmaf(v.w, w[3], acc);
    }
    out[n] = acc;
}

// ---------------- launch ----------------

extern "C" void kernel_launch(void* const* d_in, const int* in_sizes, int n_in,
                              void* d_out, int out_size, void* d_ws, size_t ws_size,
                              hipStream_t stream) {
    const float* x      = (const float*)d_in[0];
    const int*   ei     = (const int*)d_in[1];
    const float* Wl1    = (const float*)d_in[3];
    const float* bl1    = (const float*)d_in[4];
    const float* Wr1    = (const float*)d_in[5];
    const float* Wl2    = (const float*)d_in[6];
    const float* bl2    = (const float*)d_in[7];
    const float* Wr2    = (const float*)d_in[8];
    const float* Wl3    = (const float*)d_in[9];
    const float* bl3    = (const float*)d_in[10];
    const float* Wr3    = (const float*)d_in[11];
    const float* Wl4    = (const float*)d_in[12];
    const float* bl4    = (const float*)d_in[13];
    const float* Wr4    = (const float*)d_in[14];
    const float* Wl5    = (const float*)d_in[15];
    const float* bl5    = (const float*)d_in[16];
    const float* Wr5    = (const float*)d_in[17];
    const float* W_out  = (const float*)d_in[18];
    const float* b_out  = (const float*)d_in[19];
    float* out = (float*)d_out;

    const int N = N_NODES, E = N_EDGES;
    const int* e_src = ei;
    const int* e_dst = ei + E;

    size_t off = 0;
    auto carve = [&](size_t bytes) {
        void* p = (char*)d_ws + off;
        off += (bytes + 255) & ~(size_t)255;
        return p;
    };
    int*   counts  = (int*)carve((size_t)N * 4);
    int*   offsets = (int*)carve((size_t)(N + 1) * 4);
    int*   cursor  = (int*)carve((size_t)N * 4);
    float* inv_deg = (float*)carve((size_t)N * 4);
    int*   ssrc    = (int*)carve((size_t)E * 4);
    int*   bsum    = (int*)carve((size_t)512 * 4);
    float* agg     = (float*)carve((size_t)N * 128 * 4);
    float* bufA    = (float*)carve((size_t)N * 128 * 4);
    float* bufB    = (float*)carve((size_t)N * 128 * 4);

    const int scan_blocks = (N + 255) / 256;   // 391 <= 512

    // --- CSR build ---
    hipMemsetAsync(counts, 0, (size_t)N * 4, stream);
    count_deg<<<(E + 255) / 256, 256, 0, stream>>>(e_dst, counts, E);
    block_sums<<<scan_blocks, 256, 0, stream>>>(counts, bsum, N);
    scan_bsums<<<1, 512, 0, stream>>>(bsum, offsets, scan_blocks, N);
    emit_offsets<<<scan_blocks, 256, 0, stream>>>(counts, bsum, offsets, cursor, inv_deg, N);
    fill_csr<<<(E + 255) / 256, 256, 0, stream>>>(e_src, e_dst, cursor, ssrc, E);

    const int gemm_grid = (N + 127) / 128;

    // --- layer 1: 2 -> 128 ---
    aggregate2<<<(N + 255) / 256, 256, 0, stream>>>(x, offsets, ssrc, inv_deg, agg, N);
    sage_linear2<<<(N * 128 + 255) / 256, 256, 0, stream>>>(agg, x, Wl1, bl1, Wr1, bufA, N);

    // --- layer 2: 128 -> 128 ---
    aggregate4<128><<<(N * 32 + 255) / 256, 256, 0, stream>>>(bufA, offsets, ssrc, inv_deg, agg, N);
    gemm_l2<<<gemm_grid, 256, 0, stream>>>(agg, bufA, Wl2, bl2, Wr2, bufB, N);

    // --- layer 3: 128 -> 32 ---
    aggregate4<128><<<(N * 32 + 255) / 256, 256, 0, stream>>>(bufB, offsets, ssrc, inv_deg, agg, N);
    gemm_n32<128><<<gemm_grid, 256, 0, stream>>>(agg, bufB, Wl3, bl3, Wr3, bufA, N);

    // --- layer 4: 32 -> 32 ---
    aggregate4<32><<<(N * 8 + 255) / 256, 256, 0, stream>>>(bufA, offsets, ssrc, inv_deg, agg, N);
    gemm_n32<32><<<gemm_grid, 256, 0, stream>>>(agg, bufA, Wl4, bl4, Wr4, bufB, N);

    // --- layer 5: 32 -> 32 ---
    aggregate4<32><<<(N * 8 + 255) / 256, 256, 0, stream>>>(bufB, offsets, ssrc, inv_deg, agg, N);
    gemm_n32<32><<<gemm_grid, 256, 0, stream>>>(agg, bufB, Wl5, bl5, Wr5, bufA, N);

    // --- output projection ---
    out_proj<<<(N + 255) / 256, 256, 0, stream>>>(bufA, W_out, b_out, out, N);
}

// Round 5
// 688.934 us; speedup vs baseline: 3.2595x; 1.1764x over previous
//
#include <hip/hip_runtime.h>
#include <hip/hip_bf16.h>

#define N_NODES 100000
#define N_EDGES 1600000
#define NPARTS 8
#define NODES_PER_PART (N_NODES / NPARTS)   // 12500
#define BLOCKS_PER_PART 128

// ---------------- CSR build (XCD-range-partitioned scatter) ----------------

// block b handles node range (b&7); consecutive blockIdx -> different XCDs
// (round-robin heuristic; correctness never depends on the mapping).
__global__ __launch_bounds__(256) void count_deg_part(const int* __restrict__ dst,
                                                      int* __restrict__ counts, int ne) {
    int part = blockIdx.x & (NPARTS - 1);
    int sub  = blockIdx.x >> 3;
    int nblk = gridDim.x >> 3;
    int lo = part * NODES_PER_PART, hi = lo + NODES_PER_PART;
    int per = (ne + nblk - 1) / nblk;
    int b = sub * per;
    int e = min(b + per, ne);
    for (int i = b + (int)threadIdx.x; i < e; i += 256) {
        int d = dst[i];
        if (d >= lo && d < hi) atomicAdd(&counts[d], 1);
    }
}

__global__ __launch_bounds__(256) void fill_csr_part(const int* __restrict__ src,
                                                     const int* __restrict__ dst,
                                                     int* __restrict__ cursor,
                                                     int* __restrict__ sorted_src, int ne) {
    int part = blockIdx.x & (NPARTS - 1);
    int sub  = blockIdx.x >> 3;
    int nblk = gridDim.x >> 3;
    int lo = part * NODES_PER_PART, hi = lo + NODES_PER_PART;
    int per = (ne + nblk - 1) / nblk;
    int b = sub * per;
    int e = min(b + per, ne);
    for (int i = b + (int)threadIdx.x; i < e; i += 256) {
        int d = dst[i];
        int s = src[i];
        if (d >= lo && d < hi) {
            int p = atomicAdd(&cursor[d], 1);
            sorted_src[p] = s;
        }
    }
}

// phase 1: per-block (256-wide) sum of counts
__global__ __launch_bounds__(256) void block_sums(const int* __restrict__ counts,
                                                  int* __restrict__ bsum, int n) {
    int i = blockIdx.x * 256 + threadIdx.x;
    int v = (i < n) ? counts[i] : 0;
#pragma unroll
    for (int off = 32; off > 0; off >>= 1) v += __shfl_down(v, off, 64);
    __shared__ int red[4];
    if ((threadIdx.x & 63) == 0) red[threadIdx.x >> 6] = v;
    __syncthreads();
    if (threadIdx.x == 0) bsum[blockIdx.x] = red[0] + red[1] + red[2] + red[3];
}

// phase 2: single small block scans the block sums (nblocks <= 512)
__global__ __launch_bounds__(512) void scan_bsums(int* __restrict__ bsum,
                                                  int* __restrict__ offsets,
                                                  int nblocks, int n) {
    __shared__ int s[512];
    int tid = threadIdx.x;
    int v = (tid < nblocks) ? bsum[tid] : 0;
    s[tid] = v;
    __syncthreads();
    for (int off = 1; off < 512; off <<= 1) {
        int t = (tid >= off) ? s[tid - off] : 0;
        __syncthreads();
        s[tid] += t;
        __syncthreads();
    }
    if (tid < nblocks) bsum[tid] = s[tid] - v;
    if (tid == 511) offsets[n] = s[511];
}

// phase 3: per-block exclusive scan + base -> offsets, cursor, inv_deg
__global__ __launch_bounds__(256) void emit_offsets(const int* __restrict__ counts,
                                                    const int* __restrict__ bsum,
                                                    int* __restrict__ offsets,
                                                    int* __restrict__ cursor,
                                                    float* __restrict__ inv_deg, int n) {
    __shared__ int s[256];
    int tid = threadIdx.x;
    int i = blockIdx.x * 256 + tid;
    int c = (i < n) ? counts[i] : 0;
    s[tid] = c;
    __syncthreads();
    for (int off = 1; off < 256; off <<= 1) {
        int t = (tid >= off) ? s[tid - off] : 0;
        __syncthreads();
        s[tid] += t;
        __syncthreads();
    }
    if (i < n) {
        int excl = s[tid] - c + bsum[blockIdx.x];
        offsets[i] = excl;
        cursor[i] = excl;
        inv_deg[i] = 1.0f / (float)max(c, 1);
    }
}

// ---------------- aggregation ----------------

template <int Cin>
__global__ __launch_bounds__(256) void aggregate4(const float* __restrict__ h,
                                                  const int* __restrict__ offs,
                                                  const int* __restrict__ ssrc,
                                                  const float* __restrict__ inv_deg,
                                                  float* __restrict__ agg, int nnodes) {
    constexpr int C4 = Cin / 4;
    int t = blockIdx.x * blockDim.x + threadIdx.x;
    if (t >= nnodes * C4) return;
    int node = t / C4;
    int c = t - node * C4;
    int b = offs[node], e = offs[node + 1];
    const float4* __restrict__ h4 = (const float4*)h;
    float4 acc = make_float4(0.f, 0.f, 0.f, 0.f);
    for (int i = b; i < e; ++i) {
        float4 v = h4[(size_t)ssrc[i] * C4 + c];
        acc.x += v.x; acc.y += v.y; acc.z += v.z; acc.w += v.w;
    }
    float s = inv_deg[node];
    acc.x *= s; acc.y *= s; acc.z *= s; acc.w *= s;
    ((float4*)agg)[t] = acc;
}

__global__ __launch_bounds__(256) void aggregate2(const float* __restrict__ h,
                                                  const int* __restrict__ offs,
                                                  const int* __restrict__ ssrc,
                                                  const float* __restrict__ inv_deg,
                                                  float* __restrict__ agg, int nnodes) {
    int node = blockIdx.x * blockDim.x + threadIdx.x;
    if (node >= nnodes) return;
    int b = offs[node], e = offs[node + 1];
    const float2* __restrict__ h2 = (const float2*)h;
    float2 acc = make_float2(0.f, 0.f);
    for (int i = b; i < e; ++i) {
        float2 v = h2[ssrc[i]];
        acc.x += v.x; acc.y += v.y;
    }
    float s = inv_deg[node];
    acc.x *= s; acc.y *= s;
    ((float2*)agg)[node] = acc;
}

// ---------------- layer-2 GEMM: C = relu(A0@W0 + b + A1@W1), Cin=Cout=128 ----

__global__ __launch_bounds__(256) void gemm_l2(const float* __restrict__ A0,
                                               const float* __restrict__ A1,
                                               const float* __restrict__ W0,
                                               const float* __restrict__ bias,
                                               const float* __restrict__ W1,
                                               float* __restrict__ C, int M) {
    constexpr int CIN = 128, COUT = 128, BM = 128, BN = 128, BK = 8;
    __shared__ float sA0[BK][BM + 4];
    __shared__ float sA1[BK][BM + 4];
    __shared__ float sW0[BK][BN + 4];
    __shared__ float sW1[BK][BN + 4];

    const int tid = threadIdx.x;
    const int m0 = blockIdx.x * BM;
    const int tr = tid >> 4;
    const int tc = tid & 15;

    float acc[8][8];
#pragma unroll
    for (int i = 0; i < 8; ++i)
#pragma unroll
        for (int j = 0; j < 8; ++j) acc[i][j] = 0.f;

    const int arow = tid >> 1;
    const int ac4  = tid & 1;
    const int wrow = tid >> 5;
    const int wc4  = tid & 31;

    const int gr = min(m0 + arow, M - 1);

    for (int k0 = 0; k0 < CIN; k0 += BK) {
        float4 v0 = *(const float4*)&A0[(size_t)gr * CIN + k0 + ac4 * 4];
        float4 v1 = *(const float4*)&A1[(size_t)gr * CIN + k0 + ac4 * 4];
        float4 w0 = *(const float4*)&W0[(size_t)(k0 + wrow) * COUT + wc4 * 4];
        float4 w1 = *(const float4*)&W1[(size_t)(k0 + wrow) * COUT + wc4 * 4];
        sA0[ac4 * 4 + 0][arow] = v0.x; sA0[ac4 * 4 + 1][arow] = v0.y;
        sA0[ac4 * 4 + 2][arow] = v0.z; sA0[ac4 * 4 + 3][arow] = v0.w;
        sA1[ac4 * 4 + 0][arow] = v1.x; sA1[ac4 * 4 + 1][arow] = v1.y;
        sA1[ac4 * 4 + 2][arow] = v1.z; sA1[ac4 * 4 + 3][arow] = v1.w;
        *(float4*)&sW0[wrow][wc4 * 4] = w0;
        *(float4*)&sW1[wrow][wc4 * 4] = w1;
        __syncthreads();

#pragma unroll
        for (int k = 0; k < BK; ++k) {
            float4 a0l = *(const float4*)&sA0[k][tr * 8];
            float4 a0h = *(const float4*)&sA0[k][tr * 8 + 4];
            float4 a1l = *(const float4*)&sA1[k][tr * 8];
            float4 a1h = *(const float4*)&sA1[k][tr * 8 + 4];
            float4 w0l = *(const float4*)&sW0[k][tc * 8];
            float4 w0h = *(const float4*)&sW0[k][tc * 8 + 4];
            float4 w1l = *(const float4*)&sW1[k][tc * 8];
            float4 w1h = *(const float4*)&sW1[k][tc * 8 + 4];
            float a0[8] = {a0l.x, a0l.y, a0l.z, a0l.w, a0h.x, a0h.y, a0h.z, a0h.w};
            float a1[8] = {a1l.x, a1l.y, a1l.z, a1l.w, a1h.x, a1h.y, a1h.z, a1h.w};
            float w0v[8] = {w0l.x, w0l.y, w0l.z, w0l.w, w0h.x, w0h.y, w0h.z, w0h.w};
            float w1v[8] = {w1l.x, w1l.y, w1l.z, w1l.w, w1h.x, w1h.y, w1h.z, w1h.w};
#pragma unroll
            for (int i = 0; i < 8; ++i)
#pragma unroll
                for (int j = 0; j < 8; ++j)
                    acc[i][j] = fmaf(a0[i], w0v[j], fmaf(a1[i], w1v[j], acc[i][j]));
        }
        __syncthreads();
    }

#pragma unroll
    for (int i = 0; i < 8; ++i) {
        int m = m0 + tr * 8 + i;
        if (m >= M) continue;
#pragma unroll
        for (int j0 = 0; j0 < 8; j0 += 4) {
            int n = tc * 8 + j0;
            float4 bv = *(const float4*)&bias[n];
            float4 r;
            r.x = fmaxf(acc[i][j0 + 0] + bv.x, 0.f);
            r.y = fmaxf(acc[i][j0 + 1] + bv.y, 0.f);
            r.z = fmaxf(acc[i][j0 + 2] + bv.z, 0.f);
            r.w = fmaxf(acc[i][j0 + 3] + bv.w, 0.f);
            *(float4*)&C[(size_t)m * COUT + n] = r;
        }
    }
}

// ---------------- Cout=32 GEMMs ----------------
// Dual-product version (layers 4,5): C = relu(A0@W0 + b + A1@W1)

template <int Cin>
__global__ __launch_bounds__(256) void gemm_n32(const float* __restrict__ A0,
                                                const float* __restrict__ A1,
                                                const float* __restrict__ W0,
                                                const float* __restrict__ bias,
                                                const float* __restrict__ W1,
                                                float* __restrict__ C, int M) {
    constexpr int COUT = 32, BM = 128, BK = 16;
    __shared__ float sA0[BK][BM + 4];
    __shared__ float sA1[BK][BM + 4];
    __shared__ float sW0[BK][36];
    __shared__ float sW1[BK][36];

    const int tid = threadIdx.x;
    const int m0 = blockIdx.x * BM;
    const int tr = tid >> 3;
    const int tc = tid & 7;

    float acc[4][4];
#pragma unroll
    for (int i = 0; i < 4; ++i)
#pragma unroll
        for (int j = 0; j < 4; ++j) acc[i][j] = 0.f;

    const int wrow = tid >> 3;
    const int wc4  = tid & 7;

    for (int k0 = 0; k0 < Cin; k0 += BK) {
#pragma unroll
        for (int l = 0; l < 2; ++l) {
            int idx = tid + l * 256;
            int row = idx >> 2;
            int c4  = idx & 3;
            int gr  = min(m0 + row, M - 1);
            float4 v0 = *(const float4*)&A0[(size_t)gr * Cin + k0 + c4 * 4];
            float4 v1 = *(const float4*)&A1[(size_t)gr * Cin + k0 + c4 * 4];
            sA0[c4 * 4 + 0][row] = v0.x; sA0[c4 * 4 + 1][row] = v0.y;
            sA0[c4 * 4 + 2][row] = v0.z; sA0[c4 * 4 + 3][row] = v0.w;
            sA1[c4 * 4 + 0][row] = v1.x; sA1[c4 * 4 + 1][row] = v1.y;
            sA1[c4 * 4 + 2][row] = v1.z; sA1[c4 * 4 + 3][row] = v1.w;
        }
        if (tid < 128) {
            float4 w0 = *(const float4*)&W0[(size_t)(k0 + wrow) * COUT + wc4 * 4];
            float4 w1 = *(const float4*)&W1[(size_t)(k0 + wrow) * COUT + wc4 * 4];
            *(float4*)&sW0[wrow][wc4 * 4] = w0;
            *(float4*)&sW1[wrow][wc4 * 4] = w1;
        }
        __syncthreads();

#pragma unroll
        for (int k = 0; k < BK; ++k) {
            float4 a0 = *(const float4*)&sA0[k][tr * 4];
            float4 a1 = *(const float4*)&sA1[k][tr * 4];
            float4 w0 = *(const float4*)&sW0[k][tc * 4];
            float4 w1 = *(const float4*)&sW1[k][tc * 4];
            float av0[4] = {a0.x, a0.y, a0.z, a0.w};
            float av1[4] = {a1.x, a1.y, a1.z, a1.w};
            float wv0[4] = {w0.x, w0.y, w0.z, w0.w};
            float wv1[4] = {w1.x, w1.y, w1.z, w1.w};
#pragma unroll
            for (int i = 0; i < 4; ++i)
#pragma unroll
                for (int j = 0; j < 4; ++j)
                    acc[i][j] = fmaf(av0[i], wv0[j], fmaf(av1[i], wv1[j], acc[i][j]));
        }
        __syncthreads();
    }

#pragma unroll
    for (int i = 0; i < 4; ++i) {
        int m = m0 + tr * 4 + i;
        if (m >= M) continue;
        int n = tc * 4;
        float4 bv = *(const float4*)&bias[n];
        float4 r;
        r.x = fmaxf(acc[i][0] + bv.x, 0.f);
        r.y = fmaxf(acc[i][1] + bv.y, 0.f);
        r.z = fmaxf(acc[i][2] + bv.z, 0.f);
        r.w = fmaxf(acc[i][3] + bv.w, 0.f);
        *(float4*)&C[(size_t)m * COUT + n] = r;
    }
}

// Single-product, no epilogue op: C = A @ W  (layer-3 pre-transform g = h@Wl3)
template <int Cin>
__global__ __launch_bounds__(256) void gemm_pre32(const float* __restrict__ A,
                                                  const float* __restrict__ W,
                                                  float* __restrict__ C, int M) {
    constexpr int COUT = 32, BM = 128, BK = 16;
    __shared__ float sA[BK][BM + 4];
    __shared__ float sW[BK][36];

    const int tid = threadIdx.x;
    const int m0 = blockIdx.x * BM;
    const int tr = tid >> 3;
    const int tc = tid & 7;

    float acc[4][4];
#pragma unroll
    for (int i = 0; i < 4; ++i)
#pragma unroll
        for (int j = 0; j < 4; ++j) acc[i][j] = 0.f;

    const int wrow = tid >> 3;
    const int wc4  = tid & 7;

    for (int k0 = 0; k0 < Cin; k0 += BK) {
#pragma unroll
        for (int l = 0; l < 2; ++l) {
            int idx = tid + l * 256;
            int row = idx >> 2;
            int c4  = idx & 3;
            int gr  = min(m0 + row, M - 1);
            float4 v = *(const float4*)&A[(size_t)gr * Cin + k0 + c4 * 4];
            sA[c4 * 4 + 0][row] = v.x; sA[c4 * 4 + 1][row] = v.y;
            sA[c4 * 4 + 2][row] = v.z; sA[c4 * 4 + 3][row] = v.w;
        }
        if (tid < 128) {
            float4 w = *(const float4*)&W[(size_t)(k0 + wrow) * COUT + wc4 * 4];
            *(float4*)&sW[wrow][wc4 * 4] = w;
        }
        __syncthreads();

#pragma unroll
        for (int k = 0; k < BK; ++k) {
            float4 a = *(const float4*)&sA[k][tr * 4];
            float4 w = *(const float4*)&sW[k][tc * 4];
            float av[4] = {a.x, a.y, a.z, a.w};
            float wv[4] = {w.x, w.y, w.z, w.w};
#pragma unroll
            for (int i = 0; i < 4; ++i)
#pragma unroll
                for (int j = 0; j < 4; ++j)
                    acc[i][j] = fmaf(av[i], wv[j], acc[i][j]);
        }
        __syncthreads();
    }

#pragma unroll
    for (int i = 0; i < 4; ++i) {
        int m = m0 + tr * 4 + i;
        if (m >= M) continue;
        int n = tc * 4;
        float4 r = make_float4(acc[i][0], acc[i][1], acc[i][2], acc[i][3]);
        *(float4*)&C[(size_t)m * COUT + n] = r;
    }
}

// Single-product + aggregated-g add in epilogue: C = relu(agg + A@W + bias)
template <int Cin>
__global__ __launch_bounds__(256) void gemm_post32(const float* __restrict__ agg,
                                                   const float* __restrict__ A,
                                                   const float* __restrict__ W,
                                                   const float* __restrict__ bias,
                                                   float* __restrict__ C, int M) {
    constexpr int COUT = 32, BM = 128, BK = 16;
    __shared__ float sA[BK][BM + 4];
    __shared__ float sW[BK][36];

    const int tid = threadIdx.x;
    const int m0 = blockIdx.x * BM;
    const int tr = tid >> 3;
    const int tc = tid & 7;

    float acc[4][4];
#pragma unroll
    for (int i = 0; i < 4; ++i)
#pragma unroll
        for (int j = 0; j < 4; ++j) acc[i][j] = 0.f;

    const int wrow = tid >> 3;
    const int wc4  = tid & 7;

    for (int k0 = 0; k0 < Cin; k0 += BK) {
#pragma unroll
        for (int l = 0; l < 2; ++l) {
            int idx = tid + l * 256;
            int row = idx >> 2;
            int c4  = idx & 3;
            int gr  = min(m0 + row, M - 1);
            float4 v = *(const float4*)&A[(size_t)gr * Cin + k0 + c4 * 4];
            sA[c4 * 4 + 0][row] = v.x; sA[c4 * 4 + 1][row] = v.y;
            sA[c4 * 4 + 2][row] = v.z; sA[c4 * 4 + 3][row] = v.w;
        }
        if (tid < 128) {
            float4 w = *(const float4*)&W[(size_t)(k0 + wrow) * COUT + wc4 * 4];
            *(float4*)&sW[wrow][wc4 * 4] = w;
        }
        __syncthreads();

#pragma unroll
        for (int k = 0; k < BK; ++k) {
            float4 a = *(const float4*)&sA[k][tr * 4];
            float4 w = *(const float4*)&sW[k][tc * 4];
            float av[4] = {a.x, a.y, a.z, a.w};
            float wv[4] = {w.x, w.y, w.z, w.w};
#pragma unroll
            for (int i = 0; i < 4; ++i)
#pragma unroll
                for (int j = 0; j < 4; ++j)
                    acc[i][j] = fmaf(av[i], wv[j], acc[i][j]);
        }
        __syncthreads();
    }

#pragma unroll
    for (int i = 0; i < 4; ++i) {
        int m = m0 + tr * 4 + i;
        if (m >= M) continue;
        int n = tc * 4;
        float4 bv = *(const float4*)&bias[n];
        float4 gv = *(const float4*)&agg[(size_t)m * COUT + n];
        float4 r;
        r.x = fmaxf(acc[i][0] + gv.x + bv.x, 0.f);
        r.y = fmaxf(acc[i][1] + gv.y + bv.y, 0.f);
        r.z = fmaxf(acc[i][2] + gv.z + bv.z, 0.f);
        r.w = fmaxf(acc[i][3] + gv.w + bv.w, 0.f);
        *(float4*)&C[(size_t)m * COUT + n] = r;
    }
}

// layer-1 linear (Cin=2)
__global__ __launch_bounds__(256) void sage_linear2(const float* __restrict__ agg,
                                                    const float* __restrict__ h,
                                                    const float* __restrict__ Wl,
                                                    const float* __restrict__ bl,
                                                    const float* __restrict__ Wr,
                                                    float* __restrict__ out, int nnodes) {
    constexpr int Cout = 128;
    int t = blockIdx.x * blockDim.x + threadIdx.x;
    if (t >= nnodes * Cout) return;
    int node = t / Cout;
    int c = t - node * Cout;
    float2 a = ((const float2*)agg)[node];
    float2 hh = ((const float2*)h)[node];
    float acc = bl[c];
    acc = fmaf(a.x, Wl[c], acc);
    acc = fmaf(a.y, Wl[Cout + c], acc);
    acc = fmaf(hh.x, Wr[c], acc);
    acc = fmaf(hh.y, Wr[Cout + c], acc);
    out[t] = fmaxf(acc, 0.f);
}

// final projection
__global__ __launch_bounds__(256) void out_proj(const float* __restrict__ h,
                                                const float* __restrict__ W,
                                                const float* __restrict__ b,
                                                float* __restrict__ out, int nnodes) {
    int n = blockIdx.x * blockDim.x + threadIdx.x;
    if (n >= nnodes) return;
    const float4* h4 = (const float4*)(h + (size_t)n * 32);
    float acc = b[0];
#pragma unroll
    for (int k4 = 0; k4 < 8; ++k4) {
        float4 v = h4[k4];
        const float* w = W + k4 * 4;
        acc = fmaf(v.x, w[0], acc);
        acc = fmaf(v.y, w[1], acc);
        acc = fmaf(v.z, w[2], acc);
        acc = fmaf(v.w, w[3], acc);
    }
    out[n] = acc;
}

// ---------------- launch ----------------

extern "C" void kernel_launch(void* const* d_in, const int* in_sizes, int n_in,
                              void* d_out, int out_size, void* d_ws, size_t ws_size,
                              hipStream_t stream) {
    const float* x      = (const float*)d_in[0];
    const int*   ei     = (const int*)d_in[1];
    const float* Wl1    = (const float*)d_in[3];
    const float* bl1    = (const float*)d_in[4];
    const float* Wr1    = (const float*)d_in[5];
    const float* Wl2    = (const float*)d_in[6];
    const float* bl2    = (const float*)d_in[7];
    const float* Wr2    = (const float*)d_in[8];
    const float* Wl3    = (const float*)d_in[9];
    const float* bl3    = (const float*)d_in[10];
    const float* Wr3    = (const float*)d_in[11];
    const float* Wl4    = (const float*)d_in[12];
    const float* bl4    = (const float*)d_in[13];
    const float* Wr4    = (const float*)d_in[14];
    const float* Wl5    = (const float*)d_in[15];
    const float* bl5    = (const float*)d_in[16];
    const float* Wr5    = (const float*)d_in[17];
    const float* W_out  = (const float*)d_in[18];
    const float* b_out  = (const float*)d_in[19];
    float* out = (float*)d_out;

    const int N = N_NODES, E = N_EDGES;
    const int* e_src = ei;
    const int* e_dst = ei + E;

    size_t off = 0;
    auto carve = [&](size_t bytes) {
        void* p = (char*)d_ws + off;
        off += (bytes + 255) & ~(size_t)255;
        return p;
    };
    int*   counts  = (int*)carve((size_t)N * 4);
    int*   offsets = (int*)carve((size_t)(N + 1) * 4);
    int*   cursor  = (int*)carve((size_t)N * 4);
    float* inv_deg = (float*)carve((size_t)N * 4);
    int*   ssrc    = (int*)carve((size_t)E * 4);
    int*   bsum    = (int*)carve((size_t)512 * 4);
    float* agg     = (float*)carve((size_t)N * 128 * 4);  // also hosts g3/agg3 sub-buffers
    float* bufA    = (float*)carve((size_t)N * 128 * 4);
    float* bufB    = (float*)carve((size_t)N * 128 * 4);

    float* g3   = agg;                       // N x 32
    float* agg3 = agg + (size_t)N * 32;      // N x 32

    const int scan_blocks = (N + 255) / 256;   // 391 <= 512
    const int part_grid = NPARTS * BLOCKS_PER_PART;

    // --- CSR build ---
    hipMemsetAsync(counts, 0, (size_t)N * 4, stream);
    count_deg_part<<<part_grid, 256, 0, stream>>>(e_dst, counts, E);
    block_sums<<<scan_blocks, 256, 0, stream>>>(counts, bsum, N);
    scan_bsums<<<1, 512, 0, stream>>>(bsum, offsets, scan_blocks, N);
    emit_offsets<<<scan_blocks, 256, 0, stream>>>(counts, bsum, offsets, cursor, inv_deg, N);
    fill_csr_part<<<part_grid, 256, 0, stream>>>(e_src, e_dst, cursor, ssrc, E);

    const int gemm_grid = (N + 127) / 128;

    // --- layer 1: 2 -> 128 ---
    aggregate2<<<(N + 255) / 256, 256, 0, stream>>>(x, offsets, ssrc, inv_deg, agg, N);
    sage_linear2<<<(N * 128 + 255) / 256, 256, 0, stream>>>(agg, x, Wl1, bl1, Wr1, bufA, N);

    // --- layer 2: 128 -> 128 ---
    aggregate4<128><<<(N * 32 + 255) / 256, 256, 0, stream>>>(bufA, offsets, ssrc, inv_deg, agg, N);
    gemm_l2<<<gemm_grid, 256, 0, stream>>>(agg, bufA, Wl2, bl2, Wr2, bufB, N);

    // --- layer 3: 128 -> 32, via linearity: mean(h[src])@Wl = mean((h@Wl)[src]) ---
    gemm_pre32<128><<<gemm_grid, 256, 0, stream>>>(bufB, Wl3, g3, N);
    aggregate4<32><<<(N * 8 + 255) / 256, 256, 0, stream>>>(g3, offsets, ssrc, inv_deg, agg3, N);
    gemm_post32<128><<<gemm_grid, 256, 0, stream>>>(agg3, bufB, Wr3, bl3, bufA, N);

    // --- layer 4: 32 -> 32 ---
    aggregate4<32><<<(N * 8 + 255) / 256, 256, 0, stream>>>(bufA, offsets, ssrc, inv_deg, agg, N);
    gemm_n32<32><<<gemm_grid, 256, 0, stream>>>(agg, bufA, Wl4, bl4, Wr4, bufB, N);

    // --- layer 5: 32 -> 32 ---
    aggregate4<32><<<(N * 8 + 255) / 256, 256, 0, stream>>>(bufB, offsets, ssrc, inv_deg, agg, N);
    gemm_n32<32><<<gemm_grid, 256, 0, stream>>>(agg, bufB, Wl5, bl5, Wr5, bufA, N);

    // --- output projection ---
    out_proj<<<(N + 255) / 256, 256, 0, stream>>>(bufA, W_out, b_out, out, N);
}

// Round 6
// 618.228 us; speedup vs baseline: 3.6323x; 1.1144x over previous
//
#include <hip/hip_runtime.h>
#include <hip/hip_bf16.h>

#define N_NODES 100000
#define N_EDGES 1600000
#define NPARTS 8
#define NODES_PER_PART (N_NODES / NPARTS)   // 12500
#define BLOCKS_PER_PART 128

// ---------------- helpers ----------------

__device__ inline unsigned short f2bf_rne(float v) {
    unsigned u = __float_as_uint(v);
    u += 0x7fffu + ((u >> 16) & 1u);
    return (unsigned short)(u >> 16);
}

__device__ inline void acc8_bf(float* a, uint4 p) {
    a[0] += __uint_as_float(p.x << 16);
    a[1] += __uint_as_float(p.x & 0xffff0000u);
    a[2] += __uint_as_float(p.y << 16);
    a[3] += __uint_as_float(p.y & 0xffff0000u);
    a[4] += __uint_as_float(p.z << 16);
    a[5] += __uint_as_float(p.z & 0xffff0000u);
    a[6] += __uint_as_float(p.w << 16);
    a[7] += __uint_as_float(p.w & 0xffff0000u);
}

// ---------------- CSR build (XCD-range-partitioned scatter) ----------------

__global__ __launch_bounds__(256) void count_deg_part(const int* __restrict__ dst,
                                                      int* __restrict__ counts, int ne) {
    int part = blockIdx.x & (NPARTS - 1);
    int sub  = blockIdx.x >> 3;
    int nblk = gridDim.x >> 3;
    int lo = part * NODES_PER_PART, hi = lo + NODES_PER_PART;
    int per = (ne + nblk - 1) / nblk;
    int b = sub * per;
    int e = min(b + per, ne);
    for (int i = b + (int)threadIdx.x; i < e; i += 256) {
        int d = dst[i];
        if (d >= lo && d < hi) atomicAdd(&counts[d], 1);
    }
}

__global__ __launch_bounds__(256) void fill_csr_part(const int* __restrict__ src,
                                                     const int* __restrict__ dst,
                                                     int* __restrict__ cursor,
                                                     int* __restrict__ sorted_src, int ne) {
    int part = blockIdx.x & (NPARTS - 1);
    int sub  = blockIdx.x >> 3;
    int nblk = gridDim.x >> 3;
    int lo = part * NODES_PER_PART, hi = lo + NODES_PER_PART;
    int per = (ne + nblk - 1) / nblk;
    int b = sub * per;
    int e = min(b + per, ne);
    for (int i = b + (int)threadIdx.x; i < e; i += 256) {
        int d = dst[i];
        int s = src[i];
        if (d >= lo && d < hi) {
            int p = atomicAdd(&cursor[d], 1);
            sorted_src[p] = s;
        }
    }
}

__global__ __launch_bounds__(256) void block_sums(const int* __restrict__ counts,
                                                  int* __restrict__ bsum, int n) {
    int i = blockIdx.x * 256 + threadIdx.x;
    int v = (i < n) ? counts[i] : 0;
#pragma unroll
    for (int off = 32; off > 0; off >>= 1) v += __shfl_down(v, off, 64);
    __shared__ int red[4];
    if ((threadIdx.x & 63) == 0) red[threadIdx.x >> 6] = v;
    __syncthreads();
    if (threadIdx.x == 0) bsum[blockIdx.x] = red[0] + red[1] + red[2] + red[3];
}

__global__ __launch_bounds__(512) void scan_bsums(int* __restrict__ bsum,
                                                  int* __restrict__ offsets,
                                                  int nblocks, int n) {
    __shared__ int s[512];
    int tid = threadIdx.x;
    int v = (tid < nblocks) ? bsum[tid] : 0;
    s[tid] = v;
    __syncthreads();
    for (int off = 1; off < 512; off <<= 1) {
        int t = (tid >= off) ? s[tid - off] : 0;
        __syncthreads();
        s[tid] += t;
        __syncthreads();
    }
    if (tid < nblocks) bsum[tid] = s[tid] - v;
    if (tid == 511) offsets[n] = s[511];
}

__global__ __launch_bounds__(256) void emit_offsets(const int* __restrict__ counts,
                                                    const int* __restrict__ bsum,
                                                    int* __restrict__ offsets,
                                                    int* __restrict__ cursor,
                                                    float* __restrict__ inv_deg, int n) {
    __shared__ int s[256];
    int tid = threadIdx.x;
    int i = blockIdx.x * 256 + tid;
    int c = (i < n) ? counts[i] : 0;
    s[tid] = c;
    __syncthreads();
    for (int off = 1; off < 256; off <<= 1) {
        int t = (tid >= off) ? s[tid - off] : 0;
        __syncthreads();
        s[tid] += t;
        __syncthreads();
    }
    if (i < n) {
        int excl = s[tid] - c + bsum[blockIdx.x];
        offsets[i] = excl;
        cursor[i] = excl;
        inv_deg[i] = 1.0f / (float)max(c, 1);
    }
}

// ---------------- aggregation ----------------

// bf16 gather, 128 feats: 16 threads/node, 8 bf16 (16B) per thread, fp32 accum.
__global__ __launch_bounds__(256) void aggregate_bf128(const unsigned short* __restrict__ hb,
                                                       const int* __restrict__ offs,
                                                       const int* __restrict__ ssrc,
                                                       const float* __restrict__ inv_deg,
                                                       float* __restrict__ agg, int nnodes) {
    int t = blockIdx.x * 256 + threadIdx.x;
    if (t >= nnodes * 16) return;
    int node = t >> 4;
    int c = t & 15;
    int b = offs[node], e = offs[node + 1];
    const uint4* __restrict__ hb4 = (const uint4*)hb;   // 8 bf16 per uint4
    float acc[8] = {0.f, 0.f, 0.f, 0.f, 0.f, 0.f, 0.f, 0.f};
    int i = b;
    for (; i + 2 <= e; i += 2) {
        uint4 p = hb4[(size_t)ssrc[i] * 16 + c];
        uint4 q = hb4[(size_t)ssrc[i + 1] * 16 + c];
        acc8_bf(acc, p);
        acc8_bf(acc, q);
    }
    if (i < e) {
        uint4 p = hb4[(size_t)ssrc[i] * 16 + c];
        acc8_bf(acc, p);
    }
    float s = inv_deg[node];
    float4* outp = (float4*)&agg[(size_t)node * 128 + c * 8];
    outp[0] = make_float4(acc[0] * s, acc[1] * s, acc[2] * s, acc[3] * s);
    outp[1] = make_float4(acc[4] * s, acc[5] * s, acc[6] * s, acc[7] * s);
}

// fp32 gather, unrolled x2
template <int Cin>
__global__ __launch_bounds__(256) void aggregate4(const float* __restrict__ h,
                                                  const int* __restrict__ offs,
                                                  const int* __restrict__ ssrc,
                                                  const float* __restrict__ inv_deg,
                                                  float* __restrict__ agg, int nnodes) {
    constexpr int C4 = Cin / 4;
    int t = blockIdx.x * blockDim.x + threadIdx.x;
    if (t >= nnodes * C4) return;
    int node = t / C4;
    int c = t - node * C4;
    int b = offs[node], e = offs[node + 1];
    const float4* __restrict__ h4 = (const float4*)h;
    float4 a0 = make_float4(0.f, 0.f, 0.f, 0.f);
    float4 a1 = make_float4(0.f, 0.f, 0.f, 0.f);
    int i = b;
    for (; i + 2 <= e; i += 2) {
        float4 v = h4[(size_t)ssrc[i] * C4 + c];
        float4 w = h4[(size_t)ssrc[i + 1] * C4 + c];
        a0.x += v.x; a0.y += v.y; a0.z += v.z; a0.w += v.w;
        a1.x += w.x; a1.y += w.y; a1.z += w.z; a1.w += w.w;
    }
    if (i < e) {
        float4 v = h4[(size_t)ssrc[i] * C4 + c];
        a0.x += v.x; a0.y += v.y; a0.z += v.z; a0.w += v.w;
    }
    float s = inv_deg[node];
    float4 r;
    r.x = (a0.x + a1.x) * s;
    r.y = (a0.y + a1.y) * s;
    r.z = (a0.z + a1.z) * s;
    r.w = (a0.w + a1.w) * s;
    ((float4*)agg)[t] = r;
}

__global__ __launch_bounds__(256) void aggregate2(const float* __restrict__ h,
                                                  const int* __restrict__ offs,
                                                  const int* __restrict__ ssrc,
                                                  const float* __restrict__ inv_deg,
                                                  float* __restrict__ agg, int nnodes) {
    int node = blockIdx.x * blockDim.x + threadIdx.x;
    if (node >= nnodes) return;
    int b = offs[node], e = offs[node + 1];
    const float2* __restrict__ h2 = (const float2*)h;
    float2 a0 = make_float2(0.f, 0.f), a1 = make_float2(0.f, 0.f);
    int i = b;
    for (; i + 2 <= e; i += 2) {
        float2 v = h2[ssrc[i]];
        float2 w = h2[ssrc[i + 1]];
        a0.x += v.x; a0.y += v.y;
        a1.x += w.x; a1.y += w.y;
    }
    if (i < e) {
        float2 v = h2[ssrc[i]];
        a0.x += v.x; a0.y += v.y;
    }
    float s = inv_deg[node];
    ((float2*)agg)[node] = make_float2((a0.x + a1.x) * s, (a0.y + a1.y) * s);
}

// ---------------- layer-2 GEMM: C = relu(A0@W0 + b + A1@W1), Cin=Cout=128 ----

__global__ __launch_bounds__(256) void gemm_l2(const float* __restrict__ A0,
                                               const float* __restrict__ A1,
                                               const float* __restrict__ W0,
                                               const float* __restrict__ bias,
                                               const float* __restrict__ W1,
                                               float* __restrict__ C, int M) {
    constexpr int CIN = 128, COUT = 128, BM = 128, BN = 128, BK = 8;
    __shared__ float sA0[BK][BM + 4];
    __shared__ float sA1[BK][BM + 4];
    __shared__ float sW0[BK][BN + 4];
    __shared__ float sW1[BK][BN + 4];

    const int tid = threadIdx.x;
    const int m0 = blockIdx.x * BM;
    const int tr = tid >> 4;
    const int tc = tid & 15;

    float acc[8][8];
#pragma unroll
    for (int i = 0; i < 8; ++i)
#pragma unroll
        for (int j = 0; j < 8; ++j) acc[i][j] = 0.f;

    const int arow = tid >> 1;
    const int ac4  = tid & 1;
    const int wrow = tid >> 5;
    const int wc4  = tid & 31;

    const int gr = min(m0 + arow, M - 1);

    for (int k0 = 0; k0 < CIN; k0 += BK) {
        float4 v0 = *(const float4*)&A0[(size_t)gr * CIN + k0 + ac4 * 4];
        float4 v1 = *(const float4*)&A1[(size_t)gr * CIN + k0 + ac4 * 4];
        float4 w0 = *(const float4*)&W0[(size_t)(k0 + wrow) * COUT + wc4 * 4];
        float4 w1 = *(const float4*)&W1[(size_t)(k0 + wrow) * COUT + wc4 * 4];
        sA0[ac4 * 4 + 0][arow] = v0.x; sA0[ac4 * 4 + 1][arow] = v0.y;
        sA0[ac4 * 4 + 2][arow] = v0.z; sA0[ac4 * 4 + 3][arow] = v0.w;
        sA1[ac4 * 4 + 0][arow] = v1.x; sA1[ac4 * 4 + 1][arow] = v1.y;
        sA1[ac4 * 4 + 2][arow] = v1.z; sA1[ac4 * 4 + 3][arow] = v1.w;
        *(float4*)&sW0[wrow][wc4 * 4] = w0;
        *(float4*)&sW1[wrow][wc4 * 4] = w1;
        __syncthreads();

#pragma unroll
        for (int k = 0; k < BK; ++k) {
            float4 a0l = *(const float4*)&sA0[k][tr * 8];
            float4 a0h = *(const float4*)&sA0[k][tr * 8 + 4];
            float4 a1l = *(const float4*)&sA1[k][tr * 8];
            float4 a1h = *(const float4*)&sA1[k][tr * 8 + 4];
            float4 w0l = *(const float4*)&sW0[k][tc * 8];
            float4 w0h = *(const float4*)&sW0[k][tc * 8 + 4];
            float4 w1l = *(const float4*)&sW1[k][tc * 8];
            float4 w1h = *(const float4*)&sW1[k][tc * 8 + 4];
            float a0[8] = {a0l.x, a0l.y, a0l.z, a0l.w, a0h.x, a0h.y, a0h.z, a0h.w};
            float a1[8] = {a1l.x, a1l.y, a1l.z, a1l.w, a1h.x, a1h.y, a1h.z, a1h.w};
            float w0v[8] = {w0l.x, w0l.y, w0l.z, w0l.w, w0h.x, w0h.y, w0h.z, w0h.w};
            float w1v[8] = {w1l.x, w1l.y, w1l.z, w1l.w, w1h.x, w1h.y, w1h.z, w1h.w};
#pragma unroll
            for (int i = 0; i < 8; ++i)
#pragma unroll
                for (int j = 0; j < 8; ++j)
                    acc[i][j] = fmaf(a0[i], w0v[j], fmaf(a1[i], w1v[j], acc[i][j]));
        }
        __syncthreads();
    }

#pragma unroll
    for (int i = 0; i < 8; ++i) {
        int m = m0 + tr * 8 + i;
        if (m >= M) continue;
#pragma unroll
        for (int j0 = 0; j0 < 8; j0 += 4) {
            int n = tc * 8 + j0;
            float4 bv = *(const float4*)&bias[n];
            float4 r;
            r.x = fmaxf(acc[i][j0 + 0] + bv.x, 0.f);
            r.y = fmaxf(acc[i][j0 + 1] + bv.y, 0.f);
            r.z = fmaxf(acc[i][j0 + 2] + bv.z, 0.f);
            r.w = fmaxf(acc[i][j0 + 3] + bv.w, 0.f);
            *(float4*)&C[(size_t)m * COUT + n] = r;
        }
    }
}

// ---------------- Cout=32 GEMMs ----------------

template <int Cin>
__global__ __launch_bounds__(256) void gemm_n32(const float* __restrict__ A0,
                                                const float* __restrict__ A1,
                                                const float* __restrict__ W0,
                                                const float* __restrict__ bias,
                                                const float* __restrict__ W1,
                                                float* __restrict__ C, int M) {
    constexpr int COUT = 32, BM = 128, BK = 16;
    __shared__ float sA0[BK][BM + 4];
    __shared__ float sA1[BK][BM + 4];
    __shared__ float sW0[BK][36];
    __shared__ float sW1[BK][36];

    const int tid = threadIdx.x;
    const int m0 = blockIdx.x * BM;
    const int tr = tid >> 3;
    const int tc = tid & 7;

    float acc[4][4];
#pragma unroll
    for (int i = 0; i < 4; ++i)
#pragma unroll
        for (int j = 0; j < 4; ++j) acc[i][j] = 0.f;

    const int wrow = tid >> 3;
    const int wc4  = tid & 7;

    for (int k0 = 0; k0 < Cin; k0 += BK) {
#pragma unroll
        for (int l = 0; l < 2; ++l) {
            int idx = tid + l * 256;
            int row = idx >> 2;
            int c4  = idx & 3;
            int gr  = min(m0 + row, M - 1);
            float4 v0 = *(const float4*)&A0[(size_t)gr * Cin + k0 + c4 * 4];
            float4 v1 = *(const float4*)&A1[(size_t)gr * Cin + k0 + c4 * 4];
            sA0[c4 * 4 + 0][row] = v0.x; sA0[c4 * 4 + 1][row] = v0.y;
            sA0[c4 * 4 + 2][row] = v0.z; sA0[c4 * 4 + 3][row] = v0.w;
            sA1[c4 * 4 + 0][row] = v1.x; sA1[c4 * 4 + 1][row] = v1.y;
            sA1[c4 * 4 + 2][row] = v1.z; sA1[c4 * 4 + 3][row] = v1.w;
        }
        if (tid < 128) {
            float4 w0 = *(const float4*)&W0[(size_t)(k0 + wrow) * COUT + wc4 * 4];
            float4 w1 = *(const float4*)&W1[(size_t)(k0 + wrow) * COUT + wc4 * 4];
            *(float4*)&sW0[wrow][wc4 * 4] = w0;
            *(float4*)&sW1[wrow][wc4 * 4] = w1;
        }
        __syncthreads();

#pragma unroll
        for (int k = 0; k < BK; ++k) {
            float4 a0 = *(const float4*)&sA0[k][tr * 4];
            float4 a1 = *(const float4*)&sA1[k][tr * 4];
            float4 w0 = *(const float4*)&sW0[k][tc * 4];
            float4 w1 = *(const float4*)&sW1[k][tc * 4];
            float av0[4] = {a0.x, a0.y, a0.z, a0.w};
            float av1[4] = {a1.x, a1.y, a1.z, a1.w};
            float wv0[4] = {w0.x, w0.y, w0.z, w0.w};
            float wv1[4] = {w1.x, w1.y, w1.z, w1.w};
#pragma unroll
            for (int i = 0; i < 4; ++i)
#pragma unroll
                for (int j = 0; j < 4; ++j)
                    acc[i][j] = fmaf(av0[i], wv0[j], fmaf(av1[i], wv1[j], acc[i][j]));
        }
        __syncthreads();
    }

#pragma unroll
    for (int i = 0; i < 4; ++i) {
        int m = m0 + tr * 4 + i;
        if (m >= M) continue;
        int n = tc * 4;
        float4 bv = *(const float4*)&bias[n];
        float4 r;
        r.x = fmaxf(acc[i][0] + bv.x, 0.f);
        r.y = fmaxf(acc[i][1] + bv.y, 0.f);
        r.z = fmaxf(acc[i][2] + bv.z, 0.f);
        r.w = fmaxf(acc[i][3] + bv.w, 0.f);
        *(float4*)&C[(size_t)m * COUT + n] = r;
    }
}

// Single-product: C = A @ W  (layer-3 pre-transform g = h@Wl3)
template <int Cin>
__global__ __launch_bounds__(256) void gemm_pre32(const float* __restrict__ A,
                                                  const float* __restrict__ W,
                                                  float* __restrict__ C, int M) {
    constexpr int COUT = 32, BM = 128, BK = 16;
    __shared__ float sA[BK][BM + 4];
    __shared__ float sW[BK][36];

    const int tid = threadIdx.x;
    const int m0 = blockIdx.x * BM;
    const int tr = tid >> 3;
    const int tc = tid & 7;

    float acc[4][4];
#pragma unroll
    for (int i = 0; i < 4; ++i)
#pragma unroll
        for (int j = 0; j < 4; ++j) acc[i][j] = 0.f;

    const int wrow = tid >> 3;
    const int wc4  = tid & 7;

    for (int k0 = 0; k0 < Cin; k0 += BK) {
#pragma unroll
        for (int l = 0; l < 2; ++l) {
            int idx = tid + l * 256;
            int row = idx >> 2;
            int c4  = idx & 3;
            int gr  = min(m0 + row, M - 1);
            float4 v = *(const float4*)&A[(size_t)gr * Cin + k0 + c4 * 4];
            sA[c4 * 4 + 0][row] = v.x; sA[c4 * 4 + 1][row] = v.y;
            sA[c4 * 4 + 2][row] = v.z; sA[c4 * 4 + 3][row] = v.w;
        }
        if (tid < 128) {
            float4 w = *(const float4*)&W[(size_t)(k0 + wrow) * COUT + wc4 * 4];
            *(float4*)&sW[wrow][wc4 * 4] = w;
        }
        __syncthreads();

#pragma unroll
        for (int k = 0; k < BK; ++k) {
            float4 a = *(const float4*)&sA[k][tr * 4];
            float4 w = *(const float4*)&sW[k][tc * 4];
            float av[4] = {a.x, a.y, a.z, a.w};
            float wv[4] = {w.x, w.y, w.z, w.w};
#pragma unroll
            for (int i = 0; i < 4; ++i)
#pragma unroll
                for (int j = 0; j < 4; ++j)
                    acc[i][j] = fmaf(av[i], wv[j], acc[i][j]);
        }
        __syncthreads();
    }

#pragma unroll
    for (int i = 0; i < 4; ++i) {
        int m = m0 + tr * 4 + i;
        if (m >= M) continue;
        int n = tc * 4;
        *(float4*)&C[(size_t)m * COUT + n] =
            make_float4(acc[i][0], acc[i][1], acc[i][2], acc[i][3]);
    }
}

// Single-product + aggregated add: C = relu(agg + A@W + bias)
template <int Cin>
__global__ __launch_bounds__(256) void gemm_post32(const float* __restrict__ agg,
                                                   const float* __restrict__ A,
                                                   const float* __restrict__ W,
                                                   const float* __restrict__ bias,
                                                   float* __restrict__ C, int M) {
    constexpr int COUT = 32, BM = 128, BK = 16;
    __shared__ float sA[BK][BM + 4];
    __shared__ float sW[BK][36];

    const int tid = threadIdx.x;
    const int m0 = blockIdx.x * BM;
    const int tr = tid >> 3;
    const int tc = tid & 7;

    float acc[4][4];
#pragma unroll
    for (int i = 0; i < 4; ++i)
#pragma unroll
        for (int j = 0; j < 4; ++j) acc[i][j] = 0.f;

    const int wrow = tid >> 3;
    const int wc4  = tid & 7;

    for (int k0 = 0; k0 < Cin; k0 += BK) {
#pragma unroll
        for (int l = 0; l < 2; ++l) {
            int idx = tid + l * 256;
            int row = idx >> 2;
            int c4  = idx & 3;
            int gr  = min(m0 + row, M - 1);
            float4 v = *(const float4*)&A[(size_t)gr * Cin + k0 + c4 * 4];
            sA[c4 * 4 + 0][row] = v.x; sA[c4 * 4 + 1][row] = v.y;
            sA[c4 * 4 + 2][row] = v.z; sA[c4 * 4 + 3][row] = v.w;
        }
        if (tid < 128) {
            float4 w = *(const float4*)&W[(size_t)(k0 + wrow) * COUT + wc4 * 4];
            *(float4*)&sW[wrow][wc4 * 4] = w;
        }
        __syncthreads();

#pragma unroll
        for (int k = 0; k < BK; ++k) {
            float4 a = *(const float4*)&sA[k][tr * 4];
            float4 w = *(const float4*)&sW[k][tc * 4];
            float av[4] = {a.x, a.y, a.z, a.w};
            float wv[4] = {w.x, w.y, w.z, w.w};
#pragma unroll
            for (int i = 0; i < 4; ++i)
#pragma unroll
                for (int j = 0; j < 4; ++j)
                    acc[i][j] = fmaf(av[i], wv[j], acc[i][j]);
        }
        __syncthreads();
    }

#pragma unroll
    for (int i = 0; i < 4; ++i) {
        int m = m0 + tr * 4 + i;
        if (m >= M) continue;
        int n = tc * 4;
        float4 bv = *(const float4*)&bias[n];
        float4 gv = *(const float4*)&agg[(size_t)m * COUT + n];
        float4 r;
        r.x = fmaxf(acc[i][0] + gv.x + bv.x, 0.f);
        r.y = fmaxf(acc[i][1] + gv.y + bv.y, 0.f);
        r.z = fmaxf(acc[i][2] + gv.z + bv.z, 0.f);
        r.w = fmaxf(acc[i][3] + gv.w + bv.w, 0.f);
        *(float4*)&C[(size_t)m * COUT + n] = r;
    }
}

// layer-1 linear (Cin=2): fp32 out + bf16 copy for the layer-2 gather
__global__ __launch_bounds__(256) void sage_linear2(const float* __restrict__ agg,
                                                    const float* __restrict__ h,
                                                    const float* __restrict__ Wl,
                                                    const float* __restrict__ bl,
                                                    const float* __restrict__ Wr,
                                                    float* __restrict__ out,
                                                    unsigned short* __restrict__ out_bf,
                                                    int nnodes) {
    constexpr int Cout = 128;
    int t = blockIdx.x * blockDim.x + threadIdx.x;
    if (t >= nnodes * Cout) return;
    int node = t / Cout;
    int c = t - node * Cout;
    float2 a = ((const float2*)agg)[node];
    float2 hh = ((const float2*)h)[node];
    float acc = bl[c];
    acc = fmaf(a.x, Wl[c], acc);
    acc = fmaf(a.y, Wl[Cout + c], acc);
    acc = fmaf(hh.x, Wr[c], acc);
    acc = fmaf(hh.y, Wr[Cout + c], acc);
    acc = fmaxf(acc, 0.f);
    out[t] = acc;
    out_bf[t] = f2bf_rne(acc);
}

// final projection
__global__ __launch_bounds__(256) void out_proj(const float* __restrict__ h,
                                                const float* __restrict__ W,
                                                const float* __restrict__ b,
                                                float* __restrict__ out, int nnodes) {
    int n = blockIdx.x * blockDim.x + threadIdx.x;
    if (n >= nnodes) return;
    const float4* h4 = (const float4*)(h + (size_t)n * 32);
    float acc = b[0];
#pragma unroll
    for (int k4 = 0; k4 < 8; ++k4) {
        float4 v = h4[k4];
        const float* w = W + k4 * 4;
        acc = fmaf(v.x, w[0], acc);
        acc = fmaf(v.y, w[1], acc);
        acc = fmaf(v.z, w[2], acc);
        acc = fmaf(v.w, w[3], acc);
    }
    out[n] = acc;
}

// ---------------- launch ----------------

extern "C" void kernel_launch(void* const* d_in, const int* in_sizes, int n_in,
                              void* d_out, int out_size, void* d_ws, size_t ws_size,
                              hipStream_t stream) {
    const float* x      = (const float*)d_in[0];
    const int*   ei     = (const int*)d_in[1];
    const float* Wl1    = (const float*)d_in[3];
    const float* bl1    = (const float*)d_in[4];
    const float* Wr1    = (const float*)d_in[5];
    const float* Wl2    = (const float*)d_in[6];
    const float* bl2    = (const float*)d_in[7];
    const float* Wr2    = (const float*)d_in[8];
    const float* Wl3    = (const float*)d_in[9];
    const float* bl3    = (const float*)d_in[10];
    const float* Wr3    = (const float*)d_in[11];
    const float* Wl4    = (const float*)d_in[12];
    const float* bl4    = (const float*)d_in[13];
    const float* Wr4    = (const float*)d_in[14];
    const float* Wl5    = (const float*)d_in[15];
    const float* bl5    = (const float*)d_in[16];
    const float* Wr5    = (const float*)d_in[17];
    const float* W_out  = (const float*)d_in[18];
    const float* b_out  = (const float*)d_in[19];
    float* out = (float*)d_out;

    const int N = N_NODES, E = N_EDGES;
    const int* e_src = ei;
    const int* e_dst = ei + E;

    size_t off = 0;
    auto carve = [&](size_t bytes) {
        void* p = (char*)d_ws + off;
        off += (bytes + 255) & ~(size_t)255;
        return p;
    };
    int*   counts  = (int*)carve((size_t)N * 4);
    int*   offsets = (int*)carve((size_t)(N + 1) * 4);
    int*   cursor  = (int*)carve((size_t)N * 4);
    float* inv_deg = (float*)carve((size_t)N * 4);
    int*   ssrc    = (int*)carve((size_t)E * 4);
    int*   bsum    = (int*)carve((size_t)512 * 4);
    float* agg     = (float*)carve((size_t)N * 128 * 4);
    float* bufA    = (float*)carve((size_t)N * 128 * 4);
    float* bufB    = (float*)carve((size_t)N * 128 * 4);

    float* g3   = agg;                       // N x 32
    float* agg3 = agg + (size_t)N * 32;      // N x 32
    // bf16 copy of layer-1 output overlays bufB (dead until gemm_l2 writes it)
    unsigned short* bufA_bf = (unsigned short*)bufB;

    const int scan_blocks = (N + 255) / 256;   // 391 <= 512
    const int part_grid = NPARTS * BLOCKS_PER_PART;

    // --- CSR build ---
    hipMemsetAsync(counts, 0, (size_t)N * 4, stream);
    count_deg_part<<<part_grid, 256, 0, stream>>>(e_dst, counts, E);
    block_sums<<<scan_blocks, 256, 0, stream>>>(counts, bsum, N);
    scan_bsums<<<1, 512, 0, stream>>>(bsum, offsets, scan_blocks, N);
    emit_offsets<<<scan_blocks, 256, 0, stream>>>(counts, bsum, offsets, cursor, inv_deg, N);
    fill_csr_part<<<part_grid, 256, 0, stream>>>(e_src, e_dst, cursor, ssrc, E);

    const int gemm_grid = (N + 127) / 128;

    // --- layer 1: 2 -> 128 ---
    aggregate2<<<(N + 255) / 256, 256, 0, stream>>>(x, offsets, ssrc, inv_deg, agg, N);
    sage_linear2<<<(N * 128 + 255) / 256, 256, 0, stream>>>(agg, x, Wl1, bl1, Wr1,
                                                            bufA, bufA_bf, N);

    // --- layer 2: 128 -> 128 (bf16 gather) ---
    aggregate_bf128<<<(N * 16 + 255) / 256, 256, 0, stream>>>(bufA_bf, offsets, ssrc,
                                                              inv_deg, agg, N);
    gemm_l2<<<gemm_grid, 256, 0, stream>>>(agg, bufA, Wl2, bl2, Wr2, bufB, N);

    // --- layer 3: 128 -> 32, via linearity: mean(h[src])@Wl = mean((h@Wl)[src]) ---
    gemm_pre32<128><<<gemm_grid, 256, 0, stream>>>(bufB, Wl3, g3, N);
    aggregate4<32><<<(N * 8 + 255) / 256, 256, 0, stream>>>(g3, offsets, ssrc, inv_deg, agg3, N);
    gemm_post32<128><<<gemm_grid, 256, 0, stream>>>(agg3, bufB, Wr3, bl3, bufA, N);

    // --- layer 4: 32 -> 32 ---
    aggregate4<32><<<(N * 8 + 255) / 256, 256, 0, stream>>>(bufA, offsets, ssrc, inv_deg, agg, N);
    gemm_n32<32><<<gemm_grid, 256, 0, stream>>>(agg, bufA, Wl4, bl4, Wr4, bufB, N);

    // --- layer 5: 32 -> 32 ---
    aggregate4<32><<<(N * 8 + 255) / 256, 256, 0, stream>>>(bufB, offsets, ssrc, inv_deg, agg, N);
    gemm_n32<32><<<gemm_grid, 256, 0, stream>>>(agg, bufB, Wl5, bl5, Wr5, bufA, N);

    // --- output projection ---
    out_proj<<<(N + 255) / 256, 256, 0, stream>>>(bufA, W_out, b_out, out, N);
}

// Round 7
// 534.526 us; speedup vs baseline: 4.2011x; 1.1566x over previous
//
#include <hip/hip_runtime.h>
#include <hip/hip_bf16.h>

#define N_NODES 100000
#define N_EDGES 1600000
#define NPARTS 8
#define NODES_PER_PART (N_NODES / NPARTS)   // 12500
#define BLOCKS_PER_PART 128

typedef __bf16 bf16x8 __attribute__((ext_vector_type(8)));
typedef float f32x4 __attribute__((ext_vector_type(4)));

// ---------------- helpers ----------------

__device__ inline unsigned short f2bf_rne(float v) {
    unsigned u = __float_as_uint(v);
    u += 0x7fffu + ((u >> 16) & 1u);
    return (unsigned short)(u >> 16);
}

__device__ inline unsigned pack_bf(float a, float b) {
    return (unsigned)f2bf_rne(a) | ((unsigned)f2bf_rne(b) << 16);
}

__device__ inline void acc8_bf(float* a, uint4 p) {
    a[0] += __uint_as_float(p.x << 16);
    a[1] += __uint_as_float(p.x & 0xffff0000u);
    a[2] += __uint_as_float(p.y << 16);
    a[3] += __uint_as_float(p.y & 0xffff0000u);
    a[4] += __uint_as_float(p.z << 16);
    a[5] += __uint_as_float(p.z & 0xffff0000u);
    a[6] += __uint_as_float(p.w << 16);
    a[7] += __uint_as_float(p.w & 0xffff0000u);
}

// ---------------- CSR build (XCD-range-partitioned scatter) ----------------

__global__ __launch_bounds__(256) void count_deg_part(const int* __restrict__ dst,
                                                      int* __restrict__ counts, int ne) {
    int part = blockIdx.x & (NPARTS - 1);
    int sub  = blockIdx.x >> 3;
    int nblk = gridDim.x >> 3;
    int lo = part * NODES_PER_PART, hi = lo + NODES_PER_PART;
    int per = (ne + nblk - 1) / nblk;
    int b = sub * per;
    int e = min(b + per, ne);
    for (int i = b + (int)threadIdx.x; i < e; i += 256) {
        int d = dst[i];
        if (d >= lo && d < hi) atomicAdd(&counts[d], 1);
    }
}

__global__ __launch_bounds__(256) void fill_csr_part(const int* __restrict__ src,
                                                     const int* __restrict__ dst,
                                                     int* __restrict__ cursor,
                                                     int* __restrict__ sorted_src, int ne) {
    int part = blockIdx.x & (NPARTS - 1);
    int sub  = blockIdx.x >> 3;
    int nblk = gridDim.x >> 3;
    int lo = part * NODES_PER_PART, hi = lo + NODES_PER_PART;
    int per = (ne + nblk - 1) / nblk;
    int b = sub * per;
    int e = min(b + per, ne);
    for (int i = b + (int)threadIdx.x; i < e; i += 256) {
        int d = dst[i];
        int s = src[i];
        if (d >= lo && d < hi) {
            int p = atomicAdd(&cursor[d], 1);
            sorted_src[p] = s;
        }
    }
}

__global__ __launch_bounds__(256) void block_sums(const int* __restrict__ counts,
                                                  int* __restrict__ bsum, int n) {
    int i = blockIdx.x * 256 + threadIdx.x;
    int v = (i < n) ? counts[i] : 0;
#pragma unroll
    for (int off = 32; off > 0; off >>= 1) v += __shfl_down(v, off, 64);
    __shared__ int red[4];
    if ((threadIdx.x & 63) == 0) red[threadIdx.x >> 6] = v;
    __syncthreads();
    if (threadIdx.x == 0) bsum[blockIdx.x] = red[0] + red[1] + red[2] + red[3];
}

__global__ __launch_bounds__(512) void scan_bsums(int* __restrict__ bsum,
                                                  int* __restrict__ offsets,
                                                  int nblocks, int n) {
    __shared__ int s[512];
    int tid = threadIdx.x;
    int v = (tid < nblocks) ? bsum[tid] : 0;
    s[tid] = v;
    __syncthreads();
    for (int off = 1; off < 512; off <<= 1) {
        int t = (tid >= off) ? s[tid - off] : 0;
        __syncthreads();
        s[tid] += t;
        __syncthreads();
    }
    if (tid < nblocks) bsum[tid] = s[tid] - v;
    if (tid == 511) offsets[n] = s[511];
}

__global__ __launch_bounds__(256) void emit_offsets(const int* __restrict__ counts,
                                                    const int* __restrict__ bsum,
                                                    int* __restrict__ offsets,
                                                    int* __restrict__ cursor,
                                                    float* __restrict__ inv_deg, int n) {
    __shared__ int s[256];
    int tid = threadIdx.x;
    int i = blockIdx.x * 256 + tid;
    int c = (i < n) ? counts[i] : 0;
    s[tid] = c;
    __syncthreads();
    for (int off = 1; off < 256; off <<= 1) {
        int t = (tid >= off) ? s[tid - off] : 0;
        __syncthreads();
        s[tid] += t;
        __syncthreads();
    }
    if (i < n) {
        int excl = s[tid] - c + bsum[blockIdx.x];
        offsets[i] = excl;
        cursor[i] = excl;
        inv_deg[i] = 1.0f / (float)max(c, 1);
    }
}

// ---------------- aggregation ----------------

// bf16 gather, 128 feats: 16 threads/node, fp32 accum, bf16 output.
__global__ __launch_bounds__(256) void aggregate_bf128(const unsigned short* __restrict__ hb,
                                                       const int* __restrict__ offs,
                                                       const int* __restrict__ ssrc,
                                                       const float* __restrict__ inv_deg,
                                                       unsigned short* __restrict__ aggb,
                                                       int nnodes) {
    int t = blockIdx.x * 256 + threadIdx.x;
    if (t >= nnodes * 16) return;
    int node = t >> 4;
    int c = t & 15;
    int b = offs[node], e = offs[node + 1];
    const uint4* __restrict__ hb4 = (const uint4*)hb;
    float acc[8] = {0.f, 0.f, 0.f, 0.f, 0.f, 0.f, 0.f, 0.f};
    int i = b;
    for (; i + 2 <= e; i += 2) {
        uint4 p = hb4[(size_t)ssrc[i] * 16 + c];
        uint4 q = hb4[(size_t)ssrc[i + 1] * 16 + c];
        acc8_bf(acc, p);
        acc8_bf(acc, q);
    }
    if (i < e) {
        uint4 p = hb4[(size_t)ssrc[i] * 16 + c];
        acc8_bf(acc, p);
    }
    float s = inv_deg[node];
    uint4 o;
    o.x = pack_bf(acc[0] * s, acc[1] * s);
    o.y = pack_bf(acc[2] * s, acc[3] * s);
    o.z = pack_bf(acc[4] * s, acc[5] * s);
    o.w = pack_bf(acc[6] * s, acc[7] * s);
    ((uint4*)aggb)[t] = o;
}

// fp32 gather, unrolled x2
template <int Cin>
__global__ __launch_bounds__(256) void aggregate4(const float* __restrict__ h,
                                                  const int* __restrict__ offs,
                                                  const int* __restrict__ ssrc,
                                                  const float* __restrict__ inv_deg,
                                                  float* __restrict__ agg, int nnodes) {
    constexpr int C4 = Cin / 4;
    int t = blockIdx.x * blockDim.x + threadIdx.x;
    if (t >= nnodes * C4) return;
    int node = t / C4;
    int c = t - node * C4;
    int b = offs[node], e = offs[node + 1];
    const float4* __restrict__ h4 = (const float4*)h;
    float4 a0 = make_float4(0.f, 0.f, 0.f, 0.f);
    float4 a1 = make_float4(0.f, 0.f, 0.f, 0.f);
    int i = b;
    for (; i + 2 <= e; i += 2) {
        float4 v = h4[(size_t)ssrc[i] * C4 + c];
        float4 w = h4[(size_t)ssrc[i + 1] * C4 + c];
        a0.x += v.x; a0.y += v.y; a0.z += v.z; a0.w += v.w;
        a1.x += w.x; a1.y += w.y; a1.z += w.z; a1.w += w.w;
    }
    if (i < e) {
        float4 v = h4[(size_t)ssrc[i] * C4 + c];
        a0.x += v.x; a0.y += v.y; a0.z += v.z; a0.w += v.w;
    }
    float s = inv_deg[node];
    float4 r;
    r.x = (a0.x + a1.x) * s;
    r.y = (a0.y + a1.y) * s;
    r.z = (a0.z + a1.z) * s;
    r.w = (a0.w + a1.w) * s;
    ((float4*)agg)[t] = r;
}

__global__ __launch_bounds__(256) void aggregate2(const float* __restrict__ h,
                                                  const int* __restrict__ offs,
                                                  const int* __restrict__ ssrc,
                                                  const float* __restrict__ inv_deg,
                                                  float* __restrict__ agg, int nnodes) {
    int node = blockIdx.x * blockDim.x + threadIdx.x;
    if (node >= nnodes) return;
    int b = offs[node], e = offs[node + 1];
    const float2* __restrict__ h2 = (const float2*)h;
    float2 a0 = make_float2(0.f, 0.f), a1 = make_float2(0.f, 0.f);
    int i = b;
    for (; i + 2 <= e; i += 2) {
        float2 v = h2[ssrc[i]];
        float2 w = h2[ssrc[i + 1]];
        a0.x += v.x; a0.y += v.y;
        a1.x += w.x; a1.y += w.y;
    }
    if (i < e) {
        float2 v = h2[ssrc[i]];
        a0.x += v.x; a0.y += v.y;
    }
    float s = inv_deg[node];
    ((float2*)agg)[node] = make_float2((a0.x + a1.x) * s, (a0.y + a1.y) * s);
}

// ---------------- layer-2 weight prep: Wt[n][k] bf16, k = [Wl2; Wr2] --------

__global__ __launch_bounds__(256) void prep_wt(const float* __restrict__ Wl,
                                               const float* __restrict__ Wr,
                                               unsigned short* __restrict__ Wt) {
    int idx = blockIdx.x * 256 + threadIdx.x;   // 0..32767
    int n = idx >> 8;
    int k = idx & 255;
    float v = (k < 128) ? Wl[k * 128 + n] : Wr[(k - 128) * 128 + n];
    Wt[idx] = f2bf_rne(v);
}

// ---------------- layer-2 MFMA GEMM: C = relu([agg|h] @ [Wl;Wr] + b) --------
// 128x128 block tile, BK=64, 4 waves of 64x64, 4x4 grid of 16x16x32 bf16 mfma.

__global__ __launch_bounds__(256) void gemm_l2_mfma(const unsigned short* __restrict__ Ab,
                                                    const unsigned short* __restrict__ Hb,
                                                    const unsigned short* __restrict__ Wt,
                                                    const float* __restrict__ bias,
                                                    float* __restrict__ C, int M) {
    constexpr int BM = 128, BK = 64;
    __shared__ unsigned short sA[BM][BK + 8];   // +8 bf16 (16B) pad: <=2-way banks
    __shared__ unsigned short sB[128][BK + 8];

    const int tid = threadIdx.x;
    const int m0 = blockIdx.x * BM;
    const int lane = tid & 63;
    const int wid = tid >> 6;
    const int l15 = lane & 15;
    const int quad = lane >> 4;
    const int wm = (wid >> 1) * 64;
    const int wn = (wid & 1) * 64;

    f32x4 acc[4][4];
#pragma unroll
    for (int i = 0; i < 4; ++i)
#pragma unroll
        for (int j = 0; j < 4; ++j) acc[i][j] = (f32x4){0.f, 0.f, 0.f, 0.f};

    for (int k0 = 0; k0 < 256; k0 += BK) {
        const uint4* __restrict__ srcA = (const uint4*)((k0 < 128) ? Ab : Hb);
        const int kc = (k0 & 64) >> 3;   // uint4 col offset within source row
#pragma unroll
        for (int l = 0; l < 4; ++l) {
            int idx = tid + l * 256;
            int row = idx >> 3;          // 0..127
            int c8 = idx & 7;            // 8 bf16 groups
            int gr = min(m0 + row, M - 1);
            uint4 va = srcA[(size_t)gr * 16 + kc + c8];
            *(uint4*)&sA[row][c8 * 8] = va;
            uint4 vb = ((const uint4*)Wt)[(size_t)row * 32 + (k0 >> 3) + c8];
            *(uint4*)&sB[row][c8 * 8] = vb;
        }
        __syncthreads();

#pragma unroll
        for (int ks = 0; ks < BK; ks += 32) {
            bf16x8 a[4], b[4];
#pragma unroll
            for (int t = 0; t < 4; ++t) {
                a[t] = *(const bf16x8*)&sA[wm + t * 16 + l15][ks + quad * 8];
                b[t] = *(const bf16x8*)&sB[wn + t * 16 + l15][ks + quad * 8];
            }
#pragma unroll
            for (int i = 0; i < 4; ++i)
#pragma unroll
                for (int j = 0; j < 4; ++j)
                    acc[i][j] = __builtin_amdgcn_mfma_f32_16x16x32_bf16(
                        a[i], b[j], acc[i][j], 0, 0, 0);
        }
        __syncthreads();
    }

    // epilogue: bias + relu; D row = quad*4+reg, col = lane&15 (m89-verified)
#pragma unroll
    for (int j = 0; j < 4; ++j) {
        int n = wn + j * 16 + l15;
        float bv = bias[n];
#pragma unroll
        for (int i = 0; i < 4; ++i) {
#pragma unroll
            for (int r = 0; r < 4; ++r) {
                int m = m0 + wm + i * 16 + quad * 4 + r;
                if (m < M) C[(size_t)m * 128 + n] = fmaxf(acc[i][j][r] + bv, 0.f);
            }
        }
    }
}

// ---------------- Cout=32 GEMMs ----------------

template <int Cin>
__global__ __launch_bounds__(256) void gemm_n32(const float* __restrict__ A0,
                                                const float* __restrict__ A1,
                                                const float* __restrict__ W0,
                                                const float* __restrict__ bias,
                                                const float* __restrict__ W1,
                                                float* __restrict__ C, int M) {
    constexpr int COUT = 32, BM = 128, BK = 16;
    __shared__ float sA0[BK][BM + 4];
    __shared__ float sA1[BK][BM + 4];
    __shared__ float sW0[BK][36];
    __shared__ float sW1[BK][36];

    const int tid = threadIdx.x;
    const int m0 = blockIdx.x * BM;
    const int tr = tid >> 3;
    const int tc = tid & 7;

    float acc[4][4];
#pragma unroll
    for (int i = 0; i < 4; ++i)
#pragma unroll
        for (int j = 0; j < 4; ++j) acc[i][j] = 0.f;

    const int wrow = tid >> 3;
    const int wc4  = tid & 7;

    for (int k0 = 0; k0 < Cin; k0 += BK) {
#pragma unroll
        for (int l = 0; l < 2; ++l) {
            int idx = tid + l * 256;
            int row = idx >> 2;
            int c4  = idx & 3;
            int gr  = min(m0 + row, M - 1);
            float4 v0 = *(const float4*)&A0[(size_t)gr * Cin + k0 + c4 * 4];
            float4 v1 = *(const float4*)&A1[(size_t)gr * Cin + k0 + c4 * 4];
            sA0[c4 * 4 + 0][row] = v0.x; sA0[c4 * 4 + 1][row] = v0.y;
            sA0[c4 * 4 + 2][row] = v0.z; sA0[c4 * 4 + 3][row] = v0.w;
            sA1[c4 * 4 + 0][row] = v1.x; sA1[c4 * 4 + 1][row] = v1.y;
            sA1[c4 * 4 + 2][row] = v1.z; sA1[c4 * 4 + 3][row] = v1.w;
        }
        if (tid < 128) {
            float4 w0 = *(const float4*)&W0[(size_t)(k0 + wrow) * COUT + wc4 * 4];
            float4 w1 = *(const float4*)&W1[(size_t)(k0 + wrow) * COUT + wc4 * 4];
            *(float4*)&sW0[wrow][wc4 * 4] = w0;
            *(float4*)&sW1[wrow][wc4 * 4] = w1;
        }
        __syncthreads();

#pragma unroll
        for (int k = 0; k < BK; ++k) {
            float4 a0 = *(const float4*)&sA0[k][tr * 4];
            float4 a1 = *(const float4*)&sA1[k][tr * 4];
            float4 w0 = *(const float4*)&sW0[k][tc * 4];
            float4 w1 = *(const float4*)&sW1[k][tc * 4];
            float av0[4] = {a0.x, a0.y, a0.z, a0.w};
            float av1[4] = {a1.x, a1.y, a1.z, a1.w};
            float wv0[4] = {w0.x, w0.y, w0.z, w0.w};
            float wv1[4] = {w1.x, w1.y, w1.z, w1.w};
#pragma unroll
            for (int i = 0; i < 4; ++i)
#pragma unroll
                for (int j = 0; j < 4; ++j)
                    acc[i][j] = fmaf(av0[i], wv0[j], fmaf(av1[i], wv1[j], acc[i][j]));
        }
        __syncthreads();
    }

#pragma unroll
    for (int i = 0; i < 4; ++i) {
        int m = m0 + tr * 4 + i;
        if (m >= M) continue;
        int n = tc * 4;
        float4 bv = *(const float4*)&bias[n];
        float4 r;
        r.x = fmaxf(acc[i][0] + bv.x, 0.f);
        r.y = fmaxf(acc[i][1] + bv.y, 0.f);
        r.z = fmaxf(acc[i][2] + bv.z, 0.f);
        r.w = fmaxf(acc[i][3] + bv.w, 0.f);
        *(float4*)&C[(size_t)m * COUT + n] = r;
    }
}

// Single-product: C = A @ W  (layer-3 pre-transform g = h@Wl3)
template <int Cin>
__global__ __launch_bounds__(256) void gemm_pre32(const float* __restrict__ A,
                                                  const float* __restrict__ W,
                                                  float* __restrict__ C, int M) {
    constexpr int COUT = 32, BM = 128, BK = 16;
    __shared__ float sA[BK][BM + 4];
    __shared__ float sW[BK][36];

    const int tid = threadIdx.x;
    const int m0 = blockIdx.x * BM;
    const int tr = tid >> 3;
    const int tc = tid & 7;

    float acc[4][4];
#pragma unroll
    for (int i = 0; i < 4; ++i)
#pragma unroll
        for (int j = 0; j < 4; ++j) acc[i][j] = 0.f;

    const int wrow = tid >> 3;
    const int wc4  = tid & 7;

    for (int k0 = 0; k0 < Cin; k0 += BK) {
#pragma unroll
        for (int l = 0; l < 2; ++l) {
            int idx = tid + l * 256;
            int row = idx >> 2;
            int c4  = idx & 3;
            int gr  = min(m0 + row, M - 1);
            float4 v = *(const float4*)&A[(size_t)gr * Cin + k0 + c4 * 4];
            sA[c4 * 4 + 0][row] = v.x; sA[c4 * 4 + 1][row] = v.y;
            sA[c4 * 4 + 2][row] = v.z; sA[c4 * 4 + 3][row] = v.w;
        }
        if (tid < 128) {
            float4 w = *(const float4*)&W[(size_t)(k0 + wrow) * COUT + wc4 * 4];
            *(float4*)&sW[wrow][wc4 * 4] = w;
        }
        __syncthreads();

#pragma unroll
        for (int k = 0; k < BK; ++k) {
            float4 a = *(const float4*)&sA[k][tr * 4];
            float4 w = *(const float4*)&sW[k][tc * 4];
            float av[4] = {a.x, a.y, a.z, a.w};
            float wv[4] = {w.x, w.y, w.z, w.w};
#pragma unroll
            for (int i = 0; i < 4; ++i)
#pragma unroll
                for (int j = 0; j < 4; ++j)
                    acc[i][j] = fmaf(av[i], wv[j], acc[i][j]);
        }
        __syncthreads();
    }

#pragma unroll
    for (int i = 0; i < 4; ++i) {
        int m = m0 + tr * 4 + i;
        if (m >= M) continue;
        int n = tc * 4;
        *(float4*)&C[(size_t)m * COUT + n] =
            make_float4(acc[i][0], acc[i][1], acc[i][2], acc[i][3]);
    }
}

// Single-product + aggregated add: C = relu(agg + A@W + bias)
template <int Cin>
__global__ __launch_bounds__(256) void gemm_post32(const float* __restrict__ agg,
                                                   const float* __restrict__ A,
                                                   const float* __restrict__ W,
                                                   const float* __restrict__ bias,
                                                   float* __restrict__ C, int M) {
    constexpr int COUT = 32, BM = 128, BK = 16;
    __shared__ float sA[BK][BM + 4];
    __shared__ float sW[BK][36];

    const int tid = threadIdx.x;
    const int m0 = blockIdx.x * BM;
    const int tr = tid >> 3;
    const int tc = tid & 7;

    float acc[4][4];
#pragma unroll
    for (int i = 0; i < 4; ++i)
#pragma unroll
        for (int j = 0; j < 4; ++j) acc[i][j] = 0.f;

    const int wrow = tid >> 3;
    const int wc4  = tid & 7;

    for (int k0 = 0; k0 < Cin; k0 += BK) {
#pragma unroll
        for (int l = 0; l < 2; ++l) {
            int idx = tid + l * 256;
            int row = idx >> 2;
            int c4  = idx & 3;
            int gr  = min(m0 + row, M - 1);
            float4 v = *(const float4*)&A[(size_t)gr * Cin + k0 + c4 * 4];
            sA[c4 * 4 + 0][row] = v.x; sA[c4 * 4 + 1][row] = v.y;
            sA[c4 * 4 + 2][row] = v.z; sA[c4 * 4 + 3][row] = v.w;
        }
        if (tid < 128) {
            float4 w = *(const float4*)&W[(size_t)(k0 + wrow) * COUT + wc4 * 4];
            *(float4*)&sW[wrow][wc4 * 4] = w;
        }
        __syncthreads();

#pragma unroll
        for (int k = 0; k < BK; ++k) {
            float4 a = *(const float4*)&sA[k][tr * 4];
            float4 w = *(const float4*)&sW[k][tc * 4];
            float av[4] = {a.x, a.y, a.z, a.w};
            float wv[4] = {w.x, w.y, w.z, w.w};
#pragma unroll
            for (int i = 0; i < 4; ++i)
#pragma unroll
                for (int j = 0; j < 4; ++j)
                    acc[i][j] = fmaf(av[i], wv[j], acc[i][j]);
        }
        __syncthreads();
    }

#pragma unroll
    for (int i = 0; i < 4; ++i) {
        int m = m0 + tr * 4 + i;
        if (m >= M) continue;
        int n = tc * 4;
        float4 bv = *(const float4*)&bias[n];
        float4 gv = *(const float4*)&agg[(size_t)m * COUT + n];
        float4 r;
        r.x = fmaxf(acc[i][0] + gv.x + bv.x, 0.f);
        r.y = fmaxf(acc[i][1] + gv.y + bv.y, 0.f);
        r.z = fmaxf(acc[i][2] + gv.z + bv.z, 0.f);
        r.w = fmaxf(acc[i][3] + gv.w + bv.w, 0.f);
        *(float4*)&C[(size_t)m * COUT + n] = r;
    }
}

// layer-1 linear (Cin=2): bf16 output only (layer 2 consumes bf16)
__global__ __launch_bounds__(256) void sage_linear2(const float* __restrict__ agg,
                                                    const float* __restrict__ h,
                                                    const float* __restrict__ Wl,
                                                    const float* __restrict__ bl,
                                                    const float* __restrict__ Wr,
                                                    unsigned short* __restrict__ out_bf,
                                                    int nnodes) {
    constexpr int Cout = 128;
    int t = blockIdx.x * blockDim.x + threadIdx.x;
    if (t >= nnodes * Cout) return;
    int node = t / Cout;
    int c = t - node * Cout;
    float2 a = ((const float2*)agg)[node];
    float2 hh = ((const float2*)h)[node];
    float acc = bl[c];
    acc = fmaf(a.x, Wl[c], acc);
    acc = fmaf(a.y, Wl[Cout + c], acc);
    acc = fmaf(hh.x, Wr[c], acc);
    acc = fmaf(hh.y, Wr[Cout + c], acc);
    acc = fmaxf(acc, 0.f);
    out_bf[t] = f2bf_rne(acc);
}

// final projection
__global__ __launch_bounds__(256) void out_proj(const float* __restrict__ h,
                                                const float* __restrict__ W,
                                                const float* __restrict__ b,
                                                float* __restrict__ out, int nnodes) {
    int n = blockIdx.x * blockDim.x + threadIdx.x;
    if (n >= nnodes) return;
    const float4* h4 = (const float4*)(h + (size_t)n * 32);
    float acc = b[0];
#pragma unroll
    for (int k4 = 0; k4 < 8; ++k4) {
        float4 v = h4[k4];
        const float* w = W + k4 * 4;
        acc = fmaf(v.x, w[0], acc);
        acc = fmaf(v.y, w[1], acc);
        acc = fmaf(v.z, w[2], acc);
        acc = fmaf(v.w, w[3], acc);
    }
    out[n] = acc;
}

// ---------------- launch ----------------

extern "C" void kernel_launch(void* const* d_in, const int* in_sizes, int n_in,
                              void* d_out, int out_size, void* d_ws, size_t ws_size,
                              hipStream_t stream) {
    const float* x      = (const float*)d_in[0];
    const int*   ei     = (const int*)d_in[1];
    const float* Wl1    = (const float*)d_in[3];
    const float* bl1    = (const float*)d_in[4];
    const float* Wr1    = (const float*)d_in[5];
    const float* Wl2    = (const float*)d_in[6];
    const float* bl2    = (const float*)d_in[7];
    const float* Wr2    = (const float*)d_in[8];
    const float* Wl3    = (const float*)d_in[9];
    const float* bl3    = (const float*)d_in[10];
    const float* Wr3    = (const float*)d_in[11];
    const float* Wl4    = (const float*)d_in[12];
    const float* bl4    = (const float*)d_in[13];
    const float* Wr4    = (const float*)d_in[14];
    const float* Wl5    = (const float*)d_in[15];
    const float* bl5    = (const float*)d_in[16];
    const float* Wr5    = (const float*)d_in[17];
    const float* W_out  = (const float*)d_in[18];
    const float* b_out  = (const float*)d_in[19];
    float* out = (float*)d_out;

    const int N = N_NODES, E = N_EDGES;
    const int* e_src = ei;
    const int* e_dst = ei + E;

    size_t off = 0;
    auto carve = [&](size_t bytes) {
        void* p = (char*)d_ws + off;
        off += (bytes + 255) & ~(size_t)255;
        return p;
    };
    int*   counts  = (int*)carve((size_t)N * 4);
    int*   offsets = (int*)carve((size_t)(N + 1) * 4);
    int*   cursor  = (int*)carve((size_t)N * 4);
    float* inv_deg = (float*)carve((size_t)N * 4);
    int*   ssrc    = (int*)carve((size_t)E * 4);
    int*   bsum    = (int*)carve((size_t)512 * 4);
    unsigned short* Wt = (unsigned short*)carve((size_t)128 * 256 * 2);
    float* agg     = (float*)carve((size_t)N * 128 * 4);   // 4x (N x 32) fp32 slots
    float* bufA    = (float*)carve((size_t)N * 128 * 4);   // 2x (N x 128) bf16
    float* bufB    = (float*)carve((size_t)N * 128 * 4);   // layer-2 fp32 output

    // fp32 N x 32 slots inside `agg` region
    float* slotA = agg;                       // g3, later h4
    float* slotB = agg + (size_t)N * 32;      // agg3, later agg5
    float* slotC = agg + (size_t)N * 64;      // h3, later h5
    float* slotD = agg + (size_t)N * 96;      // agg4
    // bf16 N x 128 buffers inside `bufA` region
    unsigned short* h1_bf = (unsigned short*)bufA;
    unsigned short* aggB  = (unsigned short*)bufA + (size_t)N * 128;

    const int scan_blocks = (N + 255) / 256;   // 391 <= 512
    const int part_grid = NPARTS * BLOCKS_PER_PART;

    // --- CSR build + weight prep ---
    hipMemsetAsync(counts, 0, (size_t)N * 4, stream);
    count_deg_part<<<part_grid, 256, 0, stream>>>(e_dst, counts, E);
    block_sums<<<scan_blocks, 256, 0, stream>>>(counts, bsum, N);
    scan_bsums<<<1, 512, 0, stream>>>(bsum, offsets, scan_blocks, N);
    emit_offsets<<<scan_blocks, 256, 0, stream>>>(counts, bsum, offsets, cursor, inv_deg, N);
    fill_csr_part<<<part_grid, 256, 0, stream>>>(e_src, e_dst, cursor, ssrc, E);
    prep_wt<<<128, 256, 0, stream>>>(Wl2, Wr2, Wt);

    const int gemm_grid = (N + 127) / 128;

    // --- layer 1: 2 -> 128 (bf16 out) ---
    aggregate2<<<(N + 255) / 256, 256, 0, stream>>>(x, offsets, ssrc, inv_deg, slotA, N);
    sage_linear2<<<(N * 128 + 255) / 256, 256, 0, stream>>>(slotA, x, Wl1, bl1, Wr1, h1_bf, N);

    // --- layer 2: 128 -> 128, bf16 gather + MFMA GEMM ---
    aggregate_bf128<<<(N * 16 + 255) / 256, 256, 0, stream>>>(h1_bf, offsets, ssrc,
                                                              inv_deg, aggB, N);
    gemm_l2_mfma<<<gemm_grid, 256, 0, stream>>>(aggB, h1_bf, Wt, bl2, bufB, N);

    // --- layer 3: 128 -> 32, via linearity: mean(h[src])@Wl = mean((h@Wl)[src]) ---
    gemm_pre32<128><<<gemm_grid, 256, 0, stream>>>(bufB, Wl3, slotA, N);
    aggregate4<32><<<(N * 8 + 255) / 256, 256, 0, stream>>>(slotA, offsets, ssrc, inv_deg, slotB, N);
    gemm_post32<128><<<gemm_grid, 256, 0, stream>>>(slotB, bufB, Wr3, bl3, slotC, N);

    // --- layer 4: 32 -> 32 ---
    aggregate4<32><<<(N * 8 + 255) / 256, 256, 0, stream>>>(slotC, offsets, ssrc, inv_deg, slotD, N);
    gemm_n32<32><<<gemm_grid, 256, 0, stream>>>(slotD, slotC, Wl4, bl4, Wr4, slotA, N);

    // --- layer 5: 32 -> 32 ---
    aggregate4<32><<<(N * 8 + 255) / 256, 256, 0, stream>>>(slotA, offsets, ssrc, inv_deg, slotB, N);
    gemm_n32<32><<<gemm_grid, 256, 0, stream>>>(slotB, slotA, Wl5, bl5, Wr5, slotC, N);

    // --- output projection ---
    out_proj<<<(N + 255) / 256, 256, 0, stream>>>(slotC, W_out, b_out, out, N);
}

// Round 8
// 532.528 us; speedup vs baseline: 4.2168x; 1.0038x over previous
//
#include <hip/hip_runtime.h>
#include <hip/hip_bf16.h>

#define N_NODES 100000
#define N_EDGES 1600000
#define NPARTS 8
#define NODES_PER_PART (N_NODES / NPARTS)   // 12500
#define BLOCKS_PER_PART 128

typedef __bf16 bf16x8 __attribute__((ext_vector_type(8)));
typedef float f32x4 __attribute__((ext_vector_type(4)));

// ---------------- helpers ----------------

__device__ inline unsigned short f2bf_rne(float v) {
    unsigned u = __float_as_uint(v);
    u += 0x7fffu + ((u >> 16) & 1u);
    return (unsigned short)(u >> 16);
}

__device__ inline unsigned pack_bf(float a, float b) {
    return (unsigned)f2bf_rne(a) | ((unsigned)f2bf_rne(b) << 16);
}

__device__ inline void acc8_bf(float* a, uint4 p) {
    a[0] += __uint_as_float(p.x << 16);
    a[1] += __uint_as_float(p.x & 0xffff0000u);
    a[2] += __uint_as_float(p.y << 16);
    a[3] += __uint_as_float(p.y & 0xffff0000u);
    a[4] += __uint_as_float(p.z << 16);
    a[5] += __uint_as_float(p.z & 0xffff0000u);
    a[6] += __uint_as_float(p.w << 16);
    a[7] += __uint_as_float(p.w & 0xffff0000u);
}

// ---------------- CSR build (XCD-range-partitioned scatter) ----------------
// nt loads on the streamed edge arrays keep the per-part scatter window
// resident in L2 (the read stream would otherwise evict dirty lines).

__global__ __launch_bounds__(256) void count_deg_part(const int* __restrict__ dst,
                                                      int* __restrict__ counts, int ne) {
    int part = blockIdx.x & (NPARTS - 1);
    int sub  = blockIdx.x >> 3;
    int nblk = gridDim.x >> 3;
    int lo = part * NODES_PER_PART, hi = lo + NODES_PER_PART;
    int per = (ne + nblk - 1) / nblk;
    int b = sub * per;
    int e = min(b + per, ne);
    for (int i = b + (int)threadIdx.x; i < e; i += 256) {
        int d = __builtin_nontemporal_load(&dst[i]);
        if (d >= lo && d < hi) atomicAdd(&counts[d], 1);
    }
}

__global__ __launch_bounds__(256) void fill_csr_part(const int* __restrict__ src,
                                                     const int* __restrict__ dst,
                                                     int* __restrict__ cursor,
                                                     int* __restrict__ sorted_src, int ne) {
    int part = blockIdx.x & (NPARTS - 1);
    int sub  = blockIdx.x >> 3;
    int nblk = gridDim.x >> 3;
    int lo = part * NODES_PER_PART, hi = lo + NODES_PER_PART;
    int per = (ne + nblk - 1) / nblk;
    int b = sub * per;
    int e = min(b + per, ne);
    for (int i = b + (int)threadIdx.x; i < e; i += 256) {
        int d = __builtin_nontemporal_load(&dst[i]);
        int s = __builtin_nontemporal_load(&src[i]);
        if (d >= lo && d < hi) {
            int p = atomicAdd(&cursor[d], 1);
            sorted_src[p] = s;
        }
    }
}

__global__ __launch_bounds__(256) void block_sums(const int* __restrict__ counts,
                                                  int* __restrict__ bsum, int n) {
    int i = blockIdx.x * 256 + threadIdx.x;
    int v = (i < n) ? counts[i] : 0;
#pragma unroll
    for (int off = 32; off > 0; off >>= 1) v += __shfl_down(v, off, 64);
    __shared__ int red[4];
    if ((threadIdx.x & 63) == 0) red[threadIdx.x >> 6] = v;
    __syncthreads();
    if (threadIdx.x == 0) bsum[blockIdx.x] = red[0] + red[1] + red[2] + red[3];
}

__global__ __launch_bounds__(512) void scan_bsums(int* __restrict__ bsum,
                                                  int* __restrict__ offsets,
                                                  int nblocks, int n) {
    __shared__ int s[512];
    int tid = threadIdx.x;
    int v = (tid < nblocks) ? bsum[tid] : 0;
    s[tid] = v;
    __syncthreads();
    for (int off = 1; off < 512; off <<= 1) {
        int t = (tid >= off) ? s[tid - off] : 0;
        __syncthreads();
        s[tid] += t;
        __syncthreads();
    }
    if (tid < nblocks) bsum[tid] = s[tid] - v;
    if (tid == 511) offsets[n] = s[511];
}

__global__ __launch_bounds__(256) void emit_offsets(const int* __restrict__ counts,
                                                    const int* __restrict__ bsum,
                                                    int* __restrict__ offsets,
                                                    int* __restrict__ cursor,
                                                    float* __restrict__ inv_deg, int n) {
    __shared__ int s[256];
    int tid = threadIdx.x;
    int i = blockIdx.x * 256 + tid;
    int c = (i < n) ? counts[i] : 0;
    s[tid] = c;
    __syncthreads();
    for (int off = 1; off < 256; off <<= 1) {
        int t = (tid >= off) ? s[tid - off] : 0;
        __syncthreads();
        s[tid] += t;
        __syncthreads();
    }
    if (i < n) {
        int excl = s[tid] - c + bsum[blockIdx.x];
        offsets[i] = excl;
        cursor[i] = excl;
        inv_deg[i] = 1.0f / (float)max(c, 1);
    }
}

// ---------------- aggregation ----------------

// bf16 gather, 128 feats: 16 threads/node, fp32 accum, bf16 output.
__global__ __launch_bounds__(256) void aggregate_bf128(const unsigned short* __restrict__ hb,
                                                       const int* __restrict__ offs,
                                                       const int* __restrict__ ssrc,
                                                       const float* __restrict__ inv_deg,
                                                       unsigned short* __restrict__ aggb,
                                                       int nnodes) {
    int t = blockIdx.x * 256 + threadIdx.x;
    if (t >= nnodes * 16) return;
    int node = t >> 4;
    int c = t & 15;
    int b = offs[node], e = offs[node + 1];
    const uint4* __restrict__ hb4 = (const uint4*)hb;
    float acc[8] = {0.f, 0.f, 0.f, 0.f, 0.f, 0.f, 0.f, 0.f};
    int i = b;
    for (; i + 2 <= e; i += 2) {
        uint4 p = hb4[(size_t)ssrc[i] * 16 + c];
        uint4 q = hb4[(size_t)ssrc[i + 1] * 16 + c];
        acc8_bf(acc, p);
        acc8_bf(acc, q);
    }
    if (i < e) {
        uint4 p = hb4[(size_t)ssrc[i] * 16 + c];
        acc8_bf(acc, p);
    }
    float s = inv_deg[node];
    uint4 o;
    o.x = pack_bf(acc[0] * s, acc[1] * s);
    o.y = pack_bf(acc[2] * s, acc[3] * s);
    o.z = pack_bf(acc[4] * s, acc[5] * s);
    o.w = pack_bf(acc[6] * s, acc[7] * s);
    ((uint4*)aggb)[t] = o;
}

// bf16 gather, 32 feats: 4 threads/node, fp32 accum, fp32 output.
__global__ __launch_bounds__(256) void aggregate_bf32(const unsigned short* __restrict__ hb,
                                                      const int* __restrict__ offs,
                                                      const int* __restrict__ ssrc,
                                                      const float* __restrict__ inv_deg,
                                                      float* __restrict__ agg, int nnodes) {
    int t = blockIdx.x * 256 + threadIdx.x;
    if (t >= nnodes * 4) return;
    int node = t >> 2;
    int c = t & 3;
    int b = offs[node], e = offs[node + 1];
    const uint4* __restrict__ hb4 = (const uint4*)hb;   // 4 uint4 per 32-feat row
    float acc[8] = {0.f, 0.f, 0.f, 0.f, 0.f, 0.f, 0.f, 0.f};
    int i = b;
    for (; i + 2 <= e; i += 2) {
        uint4 p = hb4[(size_t)ssrc[i] * 4 + c];
        uint4 q = hb4[(size_t)ssrc[i + 1] * 4 + c];
        acc8_bf(acc, p);
        acc8_bf(acc, q);
    }
    if (i < e) {
        uint4 p = hb4[(size_t)ssrc[i] * 4 + c];
        acc8_bf(acc, p);
    }
    float s = inv_deg[node];
    float4* outp = (float4*)&agg[(size_t)node * 32 + c * 8];
    outp[0] = make_float4(acc[0] * s, acc[1] * s, acc[2] * s, acc[3] * s);
    outp[1] = make_float4(acc[4] * s, acc[5] * s, acc[6] * s, acc[7] * s);
}

__global__ __launch_bounds__(256) void aggregate2(const float* __restrict__ h,
                                                  const int* __restrict__ offs,
                                                  const int* __restrict__ ssrc,
                                                  const float* __restrict__ inv_deg,
                                                  float* __restrict__ agg, int nnodes) {
    int node = blockIdx.x * blockDim.x + threadIdx.x;
    if (node >= nnodes) return;
    int b = offs[node], e = offs[node + 1];
    const float2* __restrict__ h2 = (const float2*)h;
    float2 a0 = make_float2(0.f, 0.f), a1 = make_float2(0.f, 0.f);
    int i = b;
    for (; i + 2 <= e; i += 2) {
        float2 v = h2[ssrc[i]];
        float2 w = h2[ssrc[i + 1]];
        a0.x += v.x; a0.y += v.y;
        a1.x += w.x; a1.y += w.y;
    }
    if (i < e) {
        float2 v = h2[ssrc[i]];
        a0.x += v.x; a0.y += v.y;
    }
    float s = inv_deg[node];
    ((float2*)agg)[node] = make_float2((a0.x + a1.x) * s, (a0.y + a1.y) * s);
}

// ---------------- layer-2 weight prep: Wt[n][k] bf16, k = [Wl2; Wr2] --------

__global__ __launch_bounds__(256) void prep_wt(const float* __restrict__ Wl,
                                               const float* __restrict__ Wr,
                                               unsigned short* __restrict__ Wt) {
    int idx = blockIdx.x * 256 + threadIdx.x;   // 0..32767
    int n = idx >> 8;
    int k = idx & 255;
    float v = (k < 128) ? Wl[k * 128 + n] : Wr[(k - 128) * 128 + n];
    Wt[idx] = f2bf_rne(v);
}

// ---------------- layer-2 MFMA GEMM: C = relu([agg|h] @ [Wl;Wr] + b) --------

__global__ __launch_bounds__(256) void gemm_l2_mfma(const unsigned short* __restrict__ Ab,
                                                    const unsigned short* __restrict__ Hb,
                                                    const unsigned short* __restrict__ Wt,
                                                    const float* __restrict__ bias,
                                                    float* __restrict__ C, int M) {
    constexpr int BM = 128, BK = 64;
    __shared__ unsigned short sA[BM][BK + 8];
    __shared__ unsigned short sB[128][BK + 8];

    const int tid = threadIdx.x;
    const int m0 = blockIdx.x * BM;
    const int lane = tid & 63;
    const int wid = tid >> 6;
    const int l15 = lane & 15;
    const int quad = lane >> 4;
    const int wm = (wid >> 1) * 64;
    const int wn = (wid & 1) * 64;

    f32x4 acc[4][4];
#pragma unroll
    for (int i = 0; i < 4; ++i)
#pragma unroll
        for (int j = 0; j < 4; ++j) acc[i][j] = (f32x4){0.f, 0.f, 0.f, 0.f};

    for (int k0 = 0; k0 < 256; k0 += BK) {
        const uint4* __restrict__ srcA = (const uint4*)((k0 < 128) ? Ab : Hb);
        const int kc = (k0 & 64) >> 3;
#pragma unroll
        for (int l = 0; l < 4; ++l) {
            int idx = tid + l * 256;
            int row = idx >> 3;
            int c8 = idx & 7;
            int gr = min(m0 + row, M - 1);
            uint4 va = srcA[(size_t)gr * 16 + kc + c8];
            *(uint4*)&sA[row][c8 * 8] = va;
            uint4 vb = ((const uint4*)Wt)[(size_t)row * 32 + (k0 >> 3) + c8];
            *(uint4*)&sB[row][c8 * 8] = vb;
        }
        __syncthreads();

#pragma unroll
        for (int ks = 0; ks < BK; ks += 32) {
            bf16x8 a[4], b[4];
#pragma unroll
            for (int t = 0; t < 4; ++t) {
                a[t] = *(const bf16x8*)&sA[wm + t * 16 + l15][ks + quad * 8];
                b[t] = *(const bf16x8*)&sB[wn + t * 16 + l15][ks + quad * 8];
            }
#pragma unroll
            for (int i = 0; i < 4; ++i)
#pragma unroll
                for (int j = 0; j < 4; ++j)
                    acc[i][j] = __builtin_amdgcn_mfma_f32_16x16x32_bf16(
                        a[i], b[j], acc[i][j], 0, 0, 0);
        }
        __syncthreads();
    }

#pragma unroll
    for (int j = 0; j < 4; ++j) {
        int n = wn + j * 16 + l15;
        float bv = bias[n];
#pragma unroll
        for (int i = 0; i < 4; ++i) {
#pragma unroll
            for (int r = 0; r < 4; ++r) {
                int m = m0 + wm + i * 16 + quad * 4 + r;
                if (m < M) C[(size_t)m * 128 + n] = fmaxf(acc[i][j][r] + bv, 0.f);
            }
        }
    }
}

// ---------------- Cout=32 GEMMs ----------------

// Dual-product: C = relu(A0@W0 + b + A1@W1); optional bf16 dual-emit.
template <int Cin, bool EMIT_BF>
__global__ __launch_bounds__(256) void gemm_n32(const float* __restrict__ A0,
                                                const float* __restrict__ A1,
                                                const float* __restrict__ W0,
                                                const float* __restrict__ bias,
                                                const float* __restrict__ W1,
                                                float* __restrict__ C,
                                                unsigned short* __restrict__ Cbf, int M) {
    constexpr int COUT = 32, BM = 128, BK = 16;
    __shared__ float sA0[BK][BM + 4];
    __shared__ float sA1[BK][BM + 4];
    __shared__ float sW0[BK][36];
    __shared__ float sW1[BK][36];

    const int tid = threadIdx.x;
    const int m0 = blockIdx.x * BM;
    const int tr = tid >> 3;
    const int tc = tid & 7;

    float acc[4][4];
#pragma unroll
    for (int i = 0; i < 4; ++i)
#pragma unroll
        for (int j = 0; j < 4; ++j) acc[i][j] = 0.f;

    const int wrow = tid >> 3;
    const int wc4  = tid & 7;

    for (int k0 = 0; k0 < Cin; k0 += BK) {
#pragma unroll
        for (int l = 0; l < 2; ++l) {
            int idx = tid + l * 256;
            int row = idx >> 2;
            int c4  = idx & 3;
            int gr  = min(m0 + row, M - 1);
            float4 v0 = *(const float4*)&A0[(size_t)gr * Cin + k0 + c4 * 4];
            float4 v1 = *(const float4*)&A1[(size_t)gr * Cin + k0 + c4 * 4];
            sA0[c4 * 4 + 0][row] = v0.x; sA0[c4 * 4 + 1][row] = v0.y;
            sA0[c4 * 4 + 2][row] = v0.z; sA0[c4 * 4 + 3][row] = v0.w;
            sA1[c4 * 4 + 0][row] = v1.x; sA1[c4 * 4 + 1][row] = v1.y;
            sA1[c4 * 4 + 2][row] = v1.z; sA1[c4 * 4 + 3][row] = v1.w;
        }
        if (tid < 128) {
            float4 w0 = *(const float4*)&W0[(size_t)(k0 + wrow) * COUT + wc4 * 4];
            float4 w1 = *(const float4*)&W1[(size_t)(k0 + wrow) * COUT + wc4 * 4];
            *(float4*)&sW0[wrow][wc4 * 4] = w0;
            *(float4*)&sW1[wrow][wc4 * 4] = w1;
        }
        __syncthreads();

#pragma unroll
        for (int k = 0; k < BK; ++k) {
            float4 a0 = *(const float4*)&sA0[k][tr * 4];
            float4 a1 = *(const float4*)&sA1[k][tr * 4];
            float4 w0 = *(const float4*)&sW0[k][tc * 4];
            float4 w1 = *(const float4*)&sW1[k][tc * 4];
            float av0[4] = {a0.x, a0.y, a0.z, a0.w};
            float av1[4] = {a1.x, a1.y, a1.z, a1.w};
            float wv0[4] = {w0.x, w0.y, w0.z, w0.w};
            float wv1[4] = {w1.x, w1.y, w1.z, w1.w};
#pragma unroll
            for (int i = 0; i < 4; ++i)
#pragma unroll
                for (int j = 0; j < 4; ++j)
                    acc[i][j] = fmaf(av0[i], wv0[j], fmaf(av1[i], wv1[j], acc[i][j]));
        }
        __syncthreads();
    }

#pragma unroll
    for (int i = 0; i < 4; ++i) {
        int m = m0 + tr * 4 + i;
        if (m >= M) continue;
        int n = tc * 4;
        float4 bv = *(const float4*)&bias[n];
        float4 r;
        r.x = fmaxf(acc[i][0] + bv.x, 0.f);
        r.y = fmaxf(acc[i][1] + bv.y, 0.f);
        r.z = fmaxf(acc[i][2] + bv.z, 0.f);
        r.w = fmaxf(acc[i][3] + bv.w, 0.f);
        *(float4*)&C[(size_t)m * COUT + n] = r;
        if (EMIT_BF) {
            uint2 o;
            o.x = pack_bf(r.x, r.y);
            o.y = pack_bf(r.z, r.w);
            *(uint2*)&Cbf[(size_t)m * COUT + n] = o;
        }
    }
}

// Single-product, bf16 output only: Cbf = bf16(A @ W)  (layer-3 pre-transform)
template <int Cin>
__global__ __launch_bounds__(256) void gemm_pre32(const float* __restrict__ A,
                                                  const float* __restrict__ W,
                                                  unsigned short* __restrict__ Cbf, int M) {
    constexpr int COUT = 32, BM = 128, BK = 16;
    __shared__ float sA[BK][BM + 4];
    __shared__ float sW[BK][36];

    const int tid = threadIdx.x;
    const int m0 = blockIdx.x * BM;
    const int tr = tid >> 3;
    const int tc = tid & 7;

    float acc[4][4];
#pragma unroll
    for (int i = 0; i < 4; ++i)
#pragma unroll
        for (int j = 0; j < 4; ++j) acc[i][j] = 0.f;

    const int wrow = tid >> 3;
    const int wc4  = tid & 7;

    for (int k0 = 0; k0 < Cin; k0 += BK) {
#pragma unroll
        for (int l = 0; l < 2; ++l) {
            int idx = tid + l * 256;
            int row = idx >> 2;
            int c4  = idx & 3;
            int gr  = min(m0 + row, M - 1);
            float4 v = *(const float4*)&A[(size_t)gr * Cin + k0 + c4 * 4];
            sA[c4 * 4 + 0][row] = v.x; sA[c4 * 4 + 1][row] = v.y;
            sA[c4 * 4 + 2][row] = v.z; sA[c4 * 4 + 3][row] = v.w;
        }
        if (tid < 128) {
            float4 w = *(const float4*)&W[(size_t)(k0 + wrow) * COUT + wc4 * 4];
            *(float4*)&sW[wrow][wc4 * 4] = w;
        }
        __syncthreads();

#pragma unroll
        for (int k = 0; k < BK; ++k) {
            float4 a = *(const float4*)&sA[k][tr * 4];
            float4 w = *(const float4*)&sW[k][tc * 4];
            float av[4] = {a.x, a.y, a.z, a.w};
            float wv[4] = {w.x, w.y, w.z, w.w};
#pragma unroll
            for (int i = 0; i < 4; ++i)
#pragma unroll
                for (int j = 0; j < 4; ++j)
                    acc[i][j] = fmaf(av[i], wv[j], acc[i][j]);
        }
        __syncthreads();
    }

#pragma unroll
    for (int i = 0; i < 4; ++i) {
        int m = m0 + tr * 4 + i;
        if (m >= M) continue;
        int n = tc * 4;
        uint2 o;
        o.x = pack_bf(acc[i][0], acc[i][1]);
        o.y = pack_bf(acc[i][2], acc[i][3]);
        *(uint2*)&Cbf[(size_t)m * COUT + n] = o;
    }
}

// Single-product + aggregated add: C = relu(agg + A@W + bias), dual-emit bf16
template <int Cin>
__global__ __launch_bounds__(256) void gemm_post32(const float* __restrict__ agg,
                                                   const float* __restrict__ A,
                                                   const float* __restrict__ W,
                                                   const float* __restrict__ bias,
                                                   float* __restrict__ C,
                                                   unsigned short* __restrict__ Cbf, int M) {
    constexpr int COUT = 32, BM = 128, BK = 16;
    __shared__ float sA[BK][BM + 4];
    __shared__ float sW[BK][36];

    const int tid = threadIdx.x;
    const int m0 = blockIdx.x * BM;
    const int tr = tid >> 3;
    const int tc = tid & 7;

    float acc[4][4];
#pragma unroll
    for (int i = 0; i < 4; ++i)
#pragma unroll
        for (int j = 0; j < 4; ++j) acc[i][j] = 0.f;

    const int wrow = tid >> 3;
    const int wc4  = tid & 7;

    for (int k0 = 0; k0 < Cin; k0 += BK) {
#pragma unroll
        for (int l = 0; l < 2; ++l) {
            int idx = tid + l * 256;
            int row = idx >> 2;
            int c4  = idx & 3;
            int gr  = min(m0 + row, M - 1);
            float4 v = *(const float4*)&A[(size_t)gr * Cin + k0 + c4 * 4];
            sA[c4 * 4 + 0][row] = v.x; sA[c4 * 4 + 1][row] = v.y;
            sA[c4 * 4 + 2][row] = v.z; sA[c4 * 4 + 3][row] = v.w;
        }
        if (tid < 128) {
            float4 w = *(const float4*)&W[(size_t)(k0 + wrow) * COUT + wc4 * 4];
            *(float4*)&sW[wrow][wc4 * 4] = w;
        }
        __syncthreads();

#pragma unroll
        for (int k = 0; k < BK; ++k) {
            float4 a = *(const float4*)&sA[k][tr * 4];
            float4 w = *(const float4*)&sW[k][tc * 4];
            float av[4] = {a.x, a.y, a.z, a.w};
            float wv[4] = {w.x, w.y, w.z, w.w};
#pragma unroll
            for (int i = 0; i < 4; ++i)
#pragma unroll
                for (int j = 0; j < 4; ++j)
                    acc[i][j] = fmaf(av[i], wv[j], acc[i][j]);
        }
        __syncthreads();
    }

#pragma unroll
    for (int i = 0; i < 4; ++i) {
        int m = m0 + tr * 4 + i;
        if (m >= M) continue;
        int n = tc * 4;
        float4 bv = *(const float4*)&bias[n];
        float4 gv = *(const float4*)&agg[(size_t)m * COUT + n];
        float4 r;
        r.x = fmaxf(acc[i][0] + gv.x + bv.x, 0.f);
        r.y = fmaxf(acc[i][1] + gv.y + bv.y, 0.f);
        r.z = fmaxf(acc[i][2] + gv.z + bv.z, 0.f);
        r.w = fmaxf(acc[i][3] + gv.w + bv.w, 0.f);
        *(float4*)&C[(size_t)m * COUT + n] = r;
        uint2 o;
        o.x = pack_bf(r.x, r.y);
        o.y = pack_bf(r.z, r.w);
        *(uint2*)&Cbf[(size_t)m * COUT + n] = o;
    }
}

// layer-1 linear (Cin=2): bf16 output only
__global__ __launch_bounds__(256) void sage_linear2(const float* __restrict__ agg,
                                                    const float* __restrict__ h,
                                                    const float* __restrict__ Wl,
                                                    const float* __restrict__ bl,
                                                    const float* __restrict__ Wr,
                                                    unsigned short* __restrict__ out_bf,
                                                    int nnodes) {
    constexpr int Cout = 128;
    int t = blockIdx.x * blockDim.x + threadIdx.x;
    if (t >= nnodes * Cout) return;
    int node = t / Cout;
    int c = t - node * Cout;
    float2 a = ((const float2*)agg)[node];
    float2 hh = ((const float2*)h)[node];
    float acc = bl[c];
    acc = fmaf(a.x, Wl[c], acc);
    acc = fmaf(a.y, Wl[Cout + c], acc);
    acc = fmaf(hh.x, Wr[c], acc);
    acc = fmaf(hh.y, Wr[Cout + c], acc);
    acc = fmaxf(acc, 0.f);
    out_bf[t] = f2bf_rne(acc);
}

// final projection
__global__ __launch_bounds__(256) void out_proj(const float* __restrict__ h,
                                                const float* __restrict__ W,
                                                const float* __restrict__ b,
                                                float* __restrict__ out, int nnodes) {
    int n = blockIdx.x * blockDim.x + threadIdx.x;
    if (n >= nnodes) return;
    const float4* h4 = (const float4*)(h + (size_t)n * 32);
    float acc = b[0];
#pragma unroll
    for (int k4 = 0; k4 < 8; ++k4) {
        float4 v = h4[k4];
        const float* w = W + k4 * 4;
        acc = fmaf(v.x, w[0], acc);
        acc = fmaf(v.y, w[1], acc);
        acc = fmaf(v.z, w[2], acc);
        acc = fmaf(v.w, w[3], acc);
    }
    out[n] = acc;
}

// ---------------- launch ----------------

extern "C" void kernel_launch(void* const* d_in, const int* in_sizes, int n_in,
                              void* d_out, int out_size, void* d_ws, size_t ws_size,
                              hipStream_t stream) {
    const float* x      = (const float*)d_in[0];
    const int*   ei     = (const int*)d_in[1];
    const float* Wl1    = (const float*)d_in[3];
    const float* bl1    = (const float*)d_in[4];
    const float* Wr1    = (const float*)d_in[5];
    const float* Wl2    = (const float*)d_in[6];
    const float* bl2    = (const float*)d_in[7];
    const float* Wr2    = (const float*)d_in[8];
    const float* Wl3    = (const float*)d_in[9];
    const float* bl3    = (const float*)d_in[10];
    const float* Wr3    = (const float*)d_in[11];
    const float* Wl4    = (const float*)d_in[12];
    const float* bl4    = (const float*)d_in[13];
    const float* Wr4    = (const float*)d_in[14];
    const float* Wl5    = (const float*)d_in[15];
    const float* bl5    = (const float*)d_in[16];
    const float* Wr5    = (const float*)d_in[17];
    const float* W_out  = (const float*)d_in[18];
    const float* b_out  = (const float*)d_in[19];
    float* out = (float*)d_out;

    const int N = N_NODES, E = N_EDGES;
    const int* e_src = ei;
    const int* e_dst = ei + E;

    size_t off = 0;
    auto carve = [&](size_t bytes) {
        void* p = (char*)d_ws + off;
        off += (bytes + 255) & ~(size_t)255;
        return p;
    };
    int*   counts  = (int*)carve((size_t)N * 4);
    int*   offsets = (int*)carve((size_t)(N + 1) * 4);
    int*   cursor  = (int*)carve((size_t)N * 4);
    float* inv_deg = (float*)carve((size_t)N * 4);
    int*   ssrc    = (int*)carve((size_t)E * 4);
    int*   bsum    = (int*)carve((size_t)512 * 4);
    unsigned short* Wt = (unsigned short*)carve((size_t)128 * 256 * 2);
    float* agg     = (float*)carve((size_t)N * 128 * 4);   // 4x (N x 32) fp32 slots
    float* bufA    = (float*)carve((size_t)N * 128 * 4);   // 2x (N x 128) bf16
    float* bufB    = (float*)carve((size_t)N * 128 * 4);   // layer-2 fp32 output
    unsigned short* g3b = (unsigned short*)carve((size_t)N * 32 * 2);
    unsigned short* h3b = (unsigned short*)carve((size_t)N * 32 * 2);
    unsigned short* h4b = (unsigned short*)carve((size_t)N * 32 * 2);

    float* slotA = agg;                       // later h4
    float* slotB = agg + (size_t)N * 32;      // agg3 / agg5
    float* slotC = agg + (size_t)N * 64;      // h3 / h5
    float* slotD = agg + (size_t)N * 96;      // agg4
    unsigned short* h1_bf = (unsigned short*)bufA;
    unsigned short* aggB  = (unsigned short*)bufA + (size_t)N * 128;

    const int scan_blocks = (N + 255) / 256;   // 391 <= 512
    const int part_grid = NPARTS * BLOCKS_PER_PART;

    // --- CSR build + weight prep ---
    hipMemsetAsync(counts, 0, (size_t)N * 4, stream);
    count_deg_part<<<part_grid, 256, 0, stream>>>(e_dst, counts, E);
    block_sums<<<scan_blocks, 256, 0, stream>>>(counts, bsum, N);
    scan_bsums<<<1, 512, 0, stream>>>(bsum, offsets, scan_blocks, N);
    emit_offsets<<<scan_blocks, 256, 0, stream>>>(counts, bsum, offsets, cursor, inv_deg, N);
    fill_csr_part<<<part_grid, 256, 0, stream>>>(e_src, e_dst, cursor, ssrc, E);
    prep_wt<<<128, 256, 0, stream>>>(Wl2, Wr2, Wt);

    const int gemm_grid = (N + 127) / 128;

    // --- layer 1: 2 -> 128 (bf16 out) ---
    aggregate2<<<(N + 255) / 256, 256, 0, stream>>>(x, offsets, ssrc, inv_deg, slotA, N);
    sage_linear2<<<(N * 128 + 255) / 256, 256, 0, stream>>>(slotA, x, Wl1, bl1, Wr1, h1_bf, N);

    // --- layer 2: 128 -> 128, bf16 gather + MFMA GEMM ---
    aggregate_bf128<<<(N * 16 + 255) / 256, 256, 0, stream>>>(h1_bf, offsets, ssrc,
                                                              inv_deg, aggB, N);
    gemm_l2_mfma<<<gemm_grid, 256, 0, stream>>>(aggB, h1_bf, Wt, bl2, bufB, N);

    // --- layer 3: 128 -> 32, via linearity; bf16 gather ---
    gemm_pre32<128><<<gemm_grid, 256, 0, stream>>>(bufB, Wl3, g3b, N);
    aggregate_bf32<<<(N * 4 + 255) / 256, 256, 0, stream>>>(g3b, offsets, ssrc, inv_deg, slotB, N);
    gemm_post32<128><<<gemm_grid, 256, 0, stream>>>(slotB, bufB, Wr3, bl3, slotC, h3b, N);

    // --- layer 4: 32 -> 32 (bf16 gather) ---
    aggregate_bf32<<<(N * 4 + 255) / 256, 256, 0, stream>>>(h3b, offsets, ssrc, inv_deg, slotD, N);
    gemm_n32<32, true><<<gemm_grid, 256, 0, stream>>>(slotD, slotC, Wl4, bl4, Wr4,
                                                      slotA, h4b, N);

    // --- layer 5: 32 -> 32 (bf16 gather) ---
    aggregate_bf32<<<(N * 4 + 255) / 256, 256, 0, stream>>>(h4b, offsets, ssrc, inv_deg, slotB, N);
    gemm_n32<32, false><<<gemm_grid, 256, 0, stream>>>(slotB, slotA, Wl5, bl5, Wr5,
                                                       slotC, nullptr, N);

    // --- output projection ---
    out_proj<<<(N + 255) / 256, 256, 0, stream>>>(slotC, W_out, b_out, out, N);
}